// Round 6
// baseline (143.591 us; speedup 1.0000x reference)
//
#include <hip/hip_runtime.h>
#include <hip/hip_bf16.h>
#include <stdint.h>

// Problem constants
#define L_TOT 2304   // 48*48
#define D_IN  64
#define NF    32     // features per head
#define NH    8      // heads
#define NB    2      // batch
#define MW    256    // MLP width = NH*NF
#define CHS   4      // l-chunks for stats pass
#define NSTRIP (L_TOT/32)   // 72 m-strips
#define RT    32     // rows per k_mlp block

constexpr float EPSV  = 1e-5f;
constexpr float SCALE = 0.17677669529663687f;  // 1/sqrt(32)
constexpr float SHIFT = 20.0f;                 // softmax exp shift (s >= 0 always)

typedef __bf16  bf16x8  __attribute__((ext_vector_type(8)));
typedef float   f32x16  __attribute__((ext_vector_type(16)));

union U32x4BF { uint32_t u[4]; bf16x8 v; };

// Pack two f32 -> one u32 of two bf16 (element 0 = low halfword = a).
static __device__ __forceinline__ uint32_t pack_bf16(float a, float b) {
    union { __bf16 h[2]; uint32_t u; } r;
    r.h[0] = (__bf16)a;
    r.h[1] = (__bf16)b;
    return r.u;
}

// ---------------------------------------------------------------------------
// Kernel 0a: transpose W1,W2 -> bf16 [out][in] for MLP MFMA B-operands
// grid (8,8,2), block (32,8)
// ---------------------------------------------------------------------------
__global__ void k_prep(const float* __restrict__ W1, const float* __restrict__ W2,
                       __hip_bfloat16* __restrict__ W1t, __hip_bfloat16* __restrict__ W2t)
{
    const float* src = blockIdx.z ? W2 : W1;
    __hip_bfloat16* dst = blockIdx.z ? W2t : W1t;
    __shared__ float t[32][33];
    const int bi = blockIdx.x * 32, bj = blockIdx.y * 32;
    #pragma unroll
    for (int k = 0; k < 4; ++k)
        t[threadIdx.y + 8*k][threadIdx.x] = src[(size_t)(bi + threadIdx.y + 8*k) * MW + bj + threadIdx.x];
    __syncthreads();
    #pragma unroll
    for (int k = 0; k < 4; ++k)
        dst[(size_t)(bj + threadIdx.y + 8*k) * MW + bi + threadIdx.x] =
            __float2bfloat16(t[threadIdx.x][threadIdx.y + 8*k]);
}

// ---------------------------------------------------------------------------
// Kernel 0b: 64x32 -> 32x64 transposes to bf16:
//   jobs 0..23: Wqkv[mtx][h][d][f] -> Wt[(mtx*8+h)][f][d]
//   jobs 24..167: x[n][d][l-tile] -> xb[n][l][d]
// grid (168), block 256 (treated as 32x8)
// ---------------------------------------------------------------------------
__global__ __launch_bounds__(256) void k_prep2(
    const float* __restrict__ x,
    const float* __restrict__ Wq, const float* __restrict__ Wk, const float* __restrict__ Wv,
    __hip_bfloat16* __restrict__ xb, __hip_bfloat16* __restrict__ Wqkvt)
{
    const int job = blockIdx.x;
    const int tx = threadIdx.x & 31, ty = threadIdx.x >> 5;
    const float* src;
    size_t sstride;
    __hip_bfloat16* dst;
    if (job < 24) {
        int mtx = job >> 3, h = job & 7;
        const float* Wm = mtx == 0 ? Wq : (mtx == 1 ? Wk : Wv);
        src = Wm + (size_t)h * D_IN * NF;
        sstride = NF;
        dst = Wqkvt + (size_t)job * NF * D_IN;
    } else {
        int i = job - 24;
        int n = i / NSTRIP, lt = i % NSTRIP;
        src = x + (size_t)n * D_IN * L_TOT + lt * 32;
        sstride = L_TOT;
        dst = xb + ((size_t)n * L_TOT + lt * 32) * D_IN;
    }
    __shared__ float t[64][33];
    #pragma unroll
    for (int k = 0; k < 8; ++k)
        t[ty + 8 * k][tx] = src[(size_t)(ty + 8 * k) * sstride + tx];
    __syncthreads();
    #pragma unroll
    for (int k = 0; k < 4; ++k) {
        int col = ty + 8 * k;
        #pragma unroll
        for (int j = 0; j < 2; ++j)
            dst[(size_t)col * D_IN + tx + 32 * j] = __float2bfloat16(t[tx + 32 * j][col]);
    }
}

// ---------------------------------------------------------------------------
// Kernel 1 (MFMA proj): C[f][l] = Wt[h][f][:] . xb[l][:], +bias, InstanceNorm
// over f (register-local + one shfl), ReLU -> Qb/Kb [l][f], Vt [f][m].
// block = 256 (4 waves = 4 heads), grid = (72 ltiles, 2 n, 2 head-groups)
// ---------------------------------------------------------------------------
__global__ __launch_bounds__(256) void k_proj(
    const __hip_bfloat16* __restrict__ xb, const __hip_bfloat16* __restrict__ Wqkvt,
    const float* __restrict__ bq, const float* __restrict__ bk, const float* __restrict__ bv,
    __hip_bfloat16* __restrict__ Qo, __hip_bfloat16* __restrict__ Ko,
    __hip_bfloat16* __restrict__ Vt)
{
    const int ltile = blockIdx.x;
    const int n = blockIdx.y;
    const int h = blockIdx.z * 4 + (threadIdx.x >> 6);
    const int l0 = ltile * 32;
    const int lane = threadIdx.x & 63;
    const int c = lane & 31, hi = lane >> 5;
    const int hn = h * NB + n;

    // x B-fragments: lane c = col l0+c, k-chunk [16t+8hi, +8) along d
    const bf16x8* xp = reinterpret_cast<const bf16x8*>(
        xb + ((size_t)n * L_TOT + l0 + c) * D_IN);
    bf16x8 xf[4];
    #pragma unroll
    for (int t = 0; t < 4; ++t) xf[t] = xp[2 * t + hi];

    const float* bs[3] = {bq, bk, bv};

    #pragma unroll
    for (int mtx = 0; mtx < 3; ++mtx) {
        // W A-fragments: lane c = row f=c, same k-chunks along d
        const bf16x8* wp = reinterpret_cast<const bf16x8*>(
            Wqkvt + ((size_t)(mtx * NH + h) * NF + c) * D_IN);
        f32x16 acc = {};
        #pragma unroll
        for (int t = 0; t < 4; ++t)
            acc = __builtin_amdgcn_mfma_f32_32x32x16_bf16(wp[2 * t + hi], xf[t], acc, 0, 0, 0);

        // bias per reg: f(r,hi) = (r&3) + 8*(r>>2) + 4*hi
        float bb[16];
        #pragma unroll
        for (int g = 0; g < 4; ++g) {
            float4 t4 = *reinterpret_cast<const float4*>(&bs[mtx][h * NF + 8 * g + 4 * hi]);
            bb[4 * g + 0] = t4.x; bb[4 * g + 1] = t4.y;
            bb[4 * g + 2] = t4.z; bb[4 * g + 3] = t4.w;
        }

        float v[16], s = 0.f, s2 = 0.f;
        #pragma unroll
        for (int r = 0; r < 16; ++r) {
            v[r] = acc[r] + bb[r];
            s += v[r]; s2 += v[r] * v[r];
        }
        s  += __shfl_xor(s, 32, 64);
        s2 += __shfl_xor(s2, 32, 64);
        float mu = s * (1.f / 32);
        float rstd = rsqrtf(s2 * (1.f / 32) - mu * mu + EPSV);
        float y[16];
        #pragma unroll
        for (int r = 0; r < 16; ++r) y[r] = fmaxf((v[r] - mu) * rstd, 0.f);

        if (mtx == 2) {
            // V: Vt[hn][strip=ltile][f][m=c]
            #pragma unroll
            for (int r = 0; r < 16; ++r) {
                int f = (r & 3) + 8 * (r >> 2) + 4 * hi;
                Vt[((size_t)(hn * NSTRIP + ltile) * NF + f) * 32 + c] = __float2bfloat16(y[r]);
            }
        } else {
            if (mtx == 0) {
                #pragma unroll
                for (int r = 0; r < 16; ++r) y[r] *= SCALE;
            }
            // assemble bf16 row [l][f 0..31]: pack f-pairs, exchange across halves
            uint32_t pk[8];
            #pragma unroll
            for (int q = 0; q < 8; ++q) pk[q] = pack_bf16(y[2 * q], y[2 * q + 1]);
            uint32_t rr[4];
            #pragma unroll
            for (int j = 0; j < 4; ++j)
                rr[j] = (uint32_t)__shfl_xor((int)(hi ? pk[j] : pk[4 + j]), 32, 64);
            uint32_t row[8];
            if (hi == 0) {
                row[0] = pk[0]; row[1] = pk[1]; row[2] = rr[0]; row[3] = rr[1];
                row[4] = pk[2]; row[5] = pk[3]; row[6] = rr[2]; row[7] = rr[3];
            } else {
                row[0] = rr[0]; row[1] = rr[1]; row[2] = pk[4]; row[3] = pk[5];
                row[4] = rr[2]; row[5] = rr[3]; row[6] = pk[6]; row[7] = pk[7];
            }
            __hip_bfloat16* dst = (mtx == 0 ? Qo : Ko)
                + ((size_t)hn * L_TOT + l0 + c) * NF + hi * 16;
            reinterpret_cast<uint4*>(dst)[0] = make_uint4(row[0], row[1], row[2], row[3]);
            reinterpret_cast<uint4*>(dst)[1] = make_uint4(row[4], row[5], row[6], row[7]);
        }
    }
}

// ---------------------------------------------------------------------------
// Kernel 2: column softmax stats. S^T = K @ Q^T per 32-m strip via MFMA.
// Z[m] = sum_l exp(s - 20). Stored permuted: zpart[chunk][hn][strip*32 + hi*16 + r]
// block = 256 (4 indep waves), grid = (18, 16 hn, CHS)
// ---------------------------------------------------------------------------
__global__ __launch_bounds__(256) void k_stats(
    const __hip_bfloat16* __restrict__ Qb, const __hip_bfloat16* __restrict__ Kb,
    float* __restrict__ zpart)
{
    const int w = threadIdx.x >> 6;
    const int strip = blockIdx.x * 4 + w;
    const int hn = blockIdx.y;
    const int chunk = blockIdx.z;
    const int lane = threadIdx.x & 63;
    const int c = lane & 31, hi = lane >> 5;

    const bf16x8* kp = reinterpret_cast<const bf16x8*>(
        Kb + ((size_t)hn * L_TOT + strip * 32 + c) * NF);
    const bf16x8 ka0 = kp[hi];
    const bf16x8 ka1 = kp[2 + hi];

    float Zr[16];
    #pragma unroll
    for (int r = 0; r < 16; ++r) Zr[r] = 0.f;

    for (int it = 0; it < (L_TOT / 32) / CHS; ++it) {
        const int l0 = (chunk * ((L_TOT / 32) / CHS) + it) * 32;
        const bf16x8* qp = reinterpret_cast<const bf16x8*>(
            Qb + ((size_t)hn * L_TOT + l0 + c) * NF);
        bf16x8 qb0 = qp[hi];
        bf16x8 qb1 = qp[2 + hi];
        f32x16 s16 = {};
        s16 = __builtin_amdgcn_mfma_f32_32x32x16_bf16(ka0, qb0, s16, 0, 0, 0);
        s16 = __builtin_amdgcn_mfma_f32_32x32x16_bf16(ka1, qb1, s16, 0, 0, 0);
        #pragma unroll
        for (int r = 0; r < 16; ++r) Zr[r] += __expf(s16[r] - SHIFT);
    }
    #pragma unroll
    for (int r = 0; r < 16; ++r) {
        #pragma unroll
        for (int o = 16; o >= 1; o >>= 1) Zr[r] += __shfl_xor(Zr[r], o, 64);
    }
    if (c == 0) {
        float4* zp = reinterpret_cast<float4*>(
            zpart + ((size_t)chunk * 16 + hn) * L_TOT + strip * 32 + hi * 16);
        zp[0] = make_float4(Zr[0], Zr[1], Zr[2], Zr[3]);
        zp[1] = make_float4(Zr[4], Zr[5], Zr[6], Zr[7]);
        zp[2] = make_float4(Zr[8], Zr[9], Zr[10], Zr[11]);
        zp[3] = make_float4(Zr[12], Zr[13], Zr[14], Zr[15]);
    }
}

// Combine chunks -> lse (same permuted layout)
__global__ __launch_bounds__(256) void k_finish(
    const float* __restrict__ zpart, float* __restrict__ lse_p)
{
    const int idx = blockIdx.x * 256 + threadIdx.x;
    float Z = 0.f;
    #pragma unroll
    for (int cc = 0; cc < CHS; ++cc) Z += zpart[(size_t)cc * 16 * L_TOT + idx];
    lse_p[idx] = SHIFT + logf(Z);
}

// ---------------------------------------------------------------------------
// Kernel 3: apply. S^T via MFMA, p = exp(s - lse[m]), relayout, PV via MFMA.
// block = 256 (4 indep waves), grid = (18, 16 hn) — full m-loop (no chunking)
// ---------------------------------------------------------------------------
__global__ __launch_bounds__(256) void k_apply(
    const __hip_bfloat16* __restrict__ Qb, const __hip_bfloat16* __restrict__ Kb,
    const __hip_bfloat16* __restrict__ Vt, const float* __restrict__ lse_p,
    float* __restrict__ partA)
{
    const int w = threadIdx.x >> 6;
    const int ltile = blockIdx.x * 4 + w;
    const int l0 = ltile * 32;
    const int hn = blockIdx.y;
    const int lane = threadIdx.x & 63;
    const int c = lane & 31, hi = lane >> 5;

    const bf16x8* qp = reinterpret_cast<const bf16x8*>(
        Qb + ((size_t)hn * L_TOT + l0 + c) * NF);
    const bf16x8 qb0 = qp[hi];
    const bf16x8 qb1 = qp[2 + hi];

    f32x16 acc = {};

    for (int st = 0; st < NSTRIP; ++st) {
        const bf16x8* kp = reinterpret_cast<const bf16x8*>(
            Kb + ((size_t)hn * L_TOT + st * 32 + c) * NF);
        f32x16 s16 = {};
        s16 = __builtin_amdgcn_mfma_f32_32x32x16_bf16(kp[hi], qb0, s16, 0, 0, 0);
        s16 = __builtin_amdgcn_mfma_f32_32x32x16_bf16(kp[2 + hi], qb1, s16, 0, 0, 0);

        const float4* lp = reinterpret_cast<const float4*>(
            lse_p + (size_t)hn * L_TOT + st * 32 + hi * 16);
        float lv[16];
        #pragma unroll
        for (int q = 0; q < 4; ++q) {
            float4 t = lp[q];
            lv[4 * q + 0] = t.x; lv[4 * q + 1] = t.y;
            lv[4 * q + 2] = t.z; lv[4 * q + 3] = t.w;
        }
        float p[16];
        #pragma unroll
        for (int r = 0; r < 16; ++r) p[r] = __expf(s16[r] - lv[r]);

        uint32_t wp[8];
        #pragma unroll
        for (int q = 0; q < 8; ++q) wp[q] = pack_bf16(p[2 * q], p[2 * q + 1]);

        uint32_t sendA = hi ? wp[0] : wp[2];
        uint32_t sendB = hi ? wp[1] : wp[3];
        uint32_t rA = (uint32_t)__shfl_xor((int)sendA, 32, 64);
        uint32_t rB = (uint32_t)__shfl_xor((int)sendB, 32, 64);
        U32x4BF fragP0;
        fragP0.u[0] = hi ? rA    : wp[0];
        fragP0.u[1] = hi ? rB    : wp[1];
        fragP0.u[2] = hi ? wp[2] : rA;
        fragP0.u[3] = hi ? wp[3] : rB;
        uint32_t sendC = hi ? wp[4] : wp[6];
        uint32_t sendD = hi ? wp[5] : wp[7];
        uint32_t rC = (uint32_t)__shfl_xor((int)sendC, 32, 64);
        uint32_t rD = (uint32_t)__shfl_xor((int)sendD, 32, 64);
        U32x4BF fragP1;
        fragP1.u[0] = hi ? rC    : wp[4];
        fragP1.u[1] = hi ? rD    : wp[5];
        fragP1.u[2] = hi ? wp[6] : rC;
        fragP1.u[3] = hi ? wp[7] : rD;

        const bf16x8* vp = reinterpret_cast<const bf16x8*>(
            Vt + ((size_t)(hn * NSTRIP + st) * NF + c) * 32);
        acc = __builtin_amdgcn_mfma_f32_32x32x16_bf16(fragP0.v, vp[hi], acc, 0, 0, 0);
        acc = __builtin_amdgcn_mfma_f32_32x32x16_bf16(fragP1.v, vp[2 + hi], acc, 0, 0, 0);
    }

    const int n = hn & 1, h = hn >> 1;
    float* outp = partA + ((size_t)(n * L_TOT + l0)) * MW + h * NF + c;
    #pragma unroll
    for (int r = 0; r < 16; ++r) {
        int row = (r & 3) + 8 * (r >> 2) + 4 * hi;
        outp[(size_t)row * MW] = acc[r];
    }
}

// ---------------------------------------------------------------------------
// Kernel 4 (MFMA MLP): m=relu(relu(h@W1+b1)@W2+b2);
//   o = gamma*inorm(m+h)+beta; out[n,c,l].
// block = 512 (8 waves x 32-col groups), 32 rows/block, grid = 144
// ---------------------------------------------------------------------------
__global__ __launch_bounds__(512) void k_mlp(
    const float* __restrict__ partA,
    const __hip_bfloat16* __restrict__ W1t, const float* __restrict__ b1,
    const __hip_bfloat16* __restrict__ W2t, const float* __restrict__ b2,
    const float* __restrict__ gamma, const float* __restrict__ beta,
    float* __restrict__ out)
{
    const int blk = blockIdx.x;
    const int n  = blk / (L_TOT / RT);
    const int l0 = (blk % (L_TOT / RT)) * RT;
    const int tid = threadIdx.x;
    const int w = tid >> 6, lane = tid & 63;
    const int c = lane & 31, hi = lane >> 5;
    const int n0 = w * 32;

    __shared__ __align__(16) char smem[67584];
    float (*hsf)[MW] = reinterpret_cast<float (*)[MW]>(smem);
    __hip_bfloat16 (*hA)[264]  = reinterpret_cast<__hip_bfloat16 (*)[264]>(smem + 32768);
    __hip_bfloat16 (*msb)[264] = reinterpret_cast<__hip_bfloat16 (*)[264]>(smem + 49664);
    float (*ys)[MW] = reinterpret_cast<float (*)[MW]>(smem + 32768);
    float (*rs)[4]  = reinterpret_cast<float (*)[4]>(smem + 66560);
    float (*rs2)[4] = reinterpret_cast<float (*)[4]>(smem + 67072);

    for (int idx = tid; idx < RT * MW; idx += 512) {
        int r = idx >> 8, i = idx & 255;
        float v = partA[((size_t)n * L_TOT + l0 + r) * MW + i];
        hsf[r][i] = v;
        hA[r][i] = __float2bfloat16(v);
    }
    __syncthreads();

    // ---- layer 1 ----
    const float bb1 = b1[n0 + c];
    bf16x8 B1[16];
    #pragma unroll
    for (int k0 = 0; k0 < 16; ++k0)
        B1[k0] = *reinterpret_cast<const bf16x8*>(W1t + (size_t)(n0 + c) * MW + k0 * 16 + hi * 8);
    f32x16 acc = {};
    #pragma unroll
    for (int k0 = 0; k0 < 16; ++k0) {
        bf16x8 a = *reinterpret_cast<const bf16x8*>(&hA[c][k0 * 16 + hi * 8]);
        acc = __builtin_amdgcn_mfma_f32_32x32x16_bf16(a, B1[k0], acc, 0, 0, 0);
    }
    #pragma unroll
    for (int r = 0; r < 16; ++r) {
        int row = (r & 3) + 8 * (r >> 2) + 4 * hi;
        msb[row][n0 + c] = __float2bfloat16(fmaxf(acc[r] + bb1, 0.f));
    }
    __syncthreads();

    // ---- layer 2 + residual ----
    const float bb2 = b2[n0 + c];
    bf16x8 B2[16];
    #pragma unroll
    for (int k0 = 0; k0 < 16; ++k0)
        B2[k0] = *reinterpret_cast<const bf16x8*>(W2t + (size_t)(n0 + c) * MW + k0 * 16 + hi * 8);
    f32x16 acc2 = {};
    #pragma unroll
    for (int k0 = 0; k0 < 16; ++k0) {
        bf16x8 a = *reinterpret_cast<const bf16x8*>(&msb[c][k0 * 16 + hi * 8]);
        acc2 = __builtin_amdgcn_mfma_f32_32x32x16_bf16(a, B2[k0], acc2, 0, 0, 0);
    }
    float yv[16];
    #pragma unroll
    for (int r = 0; r < 16; ++r) {
        int row = (r & 3) + 8 * (r >> 2) + 4 * hi;
        yv[r] = fmaxf(acc2[r] + bb2, 0.f) + hsf[row][n0 + c];
    }
    __syncthreads();
    #pragma unroll
    for (int r = 0; r < 16; ++r) {
        int row = (r & 3) + 8 * (r >> 2) + 4 * hi;
        ys[row][n0 + c] = yv[r];
    }
    __syncthreads();

    // ---- instance norm over 256 channels per row + transposed store ----
    const int col = tid & 255;
    const int half = tid >> 8;
    const int wid = (tid >> 6) & 3;
    float vv[16];
    #pragma unroll
    for (int r = 0; r < 16; ++r) {
        float v = ys[half * 16 + r][col];
        vv[r] = v;
        float s = v, s2 = v * v;
        #pragma unroll
        for (int o = 32; o >= 1; o >>= 1) { s += __shfl_xor(s, o, 64); s2 += __shfl_xor(s2, o, 64); }
        if (lane == 0) { rs[half * 16 + r][wid] = s; rs2[half * 16 + r][wid] = s2; }
    }
    __syncthreads();
    const float g = gamma[col], be = beta[col];
    float ov[16];
    #pragma unroll
    for (int r = 0; r < 16; ++r) {
        int row = half * 16 + r;
        float s  = rs[row][0]  + rs[row][1]  + rs[row][2]  + rs[row][3];
        float s2 = rs2[row][0] + rs2[row][1] + rs2[row][2] + rs2[row][3];
        float mu  = s  * (1.f / MW);
        float var = s2 * (1.f / MW) - mu * mu;
        ov[r] = g * ((vv[r] - mu) * rsqrtf(var + EPSV)) + be;
    }
    float* ob = out + ((size_t)n * MW + col) * L_TOT + l0 + half * 16;
    #pragma unroll
    for (int q = 0; q < 4; ++q)
        reinterpret_cast<float4*>(ob)[q] =
            make_float4(ov[4 * q], ov[4 * q + 1], ov[4 * q + 2], ov[4 * q + 3]);
}

// ---------------------------------------------------------------------------
extern "C" void kernel_launch(void* const* d_in, const int* in_sizes, int n_in,
                              void* d_out, int out_size, void* d_ws, size_t ws_size,
                              hipStream_t stream) {
    const float* x  = (const float*)d_in[0];
    const float* Wq = (const float*)d_in[1];
    const float* bq = (const float*)d_in[2];
    const float* Wk = (const float*)d_in[3];
    const float* bk = (const float*)d_in[4];
    const float* Wv = (const float*)d_in[5];
    const float* bv = (const float*)d_in[6];
    const float* W1 = (const float*)d_in[7];
    const float* b1 = (const float*)d_in[8];
    const float* W2 = (const float*)d_in[9];
    const float* b2 = (const float*)d_in[10];
    const float* gm = (const float*)d_in[11];
    const float* bt = (const float*)d_in[12];
    float* out = (float*)d_out;

    const size_t QKVE = (size_t)16 * L_TOT * NF;   // 1,179,648 bf16 elems each
    const size_t XBE  = (size_t)NB * L_TOT * D_IN; // 294,912
    const size_t WQE  = (size_t)3 * NH * NF * D_IN;// 49,152
    const size_t WTE  = (size_t)MW * MW;           // 65,536 per matrix
    const size_t ZN = (size_t)CHS * 16 * L_TOT;
    const size_t LN = (size_t)16 * L_TOT;

    __hip_bfloat16* Qb = (__hip_bfloat16*)d_ws;
    __hip_bfloat16* Kb = Qb + QKVE;
    __hip_bfloat16* Vt = Kb + QKVE;
    __hip_bfloat16* xb = Vt + QKVE;
    __hip_bfloat16* Wqkvt = xb + XBE;
    __hip_bfloat16* W1t = Wqkvt + WQE;
    __hip_bfloat16* W2t = W1t + WTE;
    float* zpart = (float*)(W2t + WTE);
    float* lse_p = zpart + ZN;
    float* partA = lse_p + LN;

    k_prep<<<dim3(8, 8, 2), dim3(32, 8), 0, stream>>>(W1, W2, W1t, W2t);
    k_prep2<<<dim3(24 + NB * NSTRIP), dim3(256), 0, stream>>>(x, Wq, Wk, Wv, xb, Wqkvt);
    k_proj<<<dim3(NSTRIP, NB, 2), dim3(256), 0, stream>>>(
        xb, Wqkvt, bq, bk, bv, Qb, Kb, Vt);
    k_stats<<<dim3(NSTRIP / 4, 16, CHS), dim3(256), 0, stream>>>(Qb, Kb, zpart);
    k_finish<<<dim3(16 * L_TOT / 256), dim3(256), 0, stream>>>(zpart, lse_p);
    k_apply<<<dim3(NSTRIP / 4, 16), dim3(256), 0, stream>>>(
        Qb, Kb, Vt, lse_p, partA);
    k_mlp<<<dim3(NB * (L_TOT / RT)), dim3(512), 0, stream>>>(
        partA, W1t, b1, W2t, b2, gm, bt, out);
}

// Round 7
// 131.658 us; speedup vs baseline: 1.0906x; 1.0906x over previous
//
#include <hip/hip_runtime.h>
#include <hip/hip_bf16.h>
#include <stdint.h>

// Problem constants
#define L_TOT 2304   // 48*48
#define D_IN  64
#define NF    32     // features per head
#define NH    8      // heads
#define NB    2      // batch
#define MW    256    // MLP width = NH*NF
#define CHS   4      // l-chunks for stats pass
#define NSTRIP (L_TOT/32)   // 72 m-strips
#define RT    32     // rows per k_mlp block

constexpr float EPSV  = 1e-5f;
constexpr float SCALE = 0.17677669529663687f;  // 1/sqrt(32)
constexpr float SHIFT = 20.0f;                 // softmax exp shift (s >= 0 always)

typedef __bf16  bf16x8  __attribute__((ext_vector_type(8)));
typedef float   f32x16  __attribute__((ext_vector_type(16)));

union U32x4BF { uint32_t u[4]; bf16x8 v; };

// Pack two f32 -> one u32 of two bf16 (element 0 = low halfword = a).
static __device__ __forceinline__ uint32_t pack_bf16(float a, float b) {
    union { __bf16 h[2]; uint32_t u; } r;
    r.h[0] = (__bf16)a;
    r.h[1] = (__bf16)b;
    return r.u;
}

// ---------------------------------------------------------------------------
// Kernel 0a: transpose W1,W2 -> bf16 [out][in] for MLP MFMA B-operands
// ---------------------------------------------------------------------------
__global__ void k_prep(const float* __restrict__ W1, const float* __restrict__ W2,
                       __hip_bfloat16* __restrict__ W1t, __hip_bfloat16* __restrict__ W2t)
{
    const float* src = blockIdx.z ? W2 : W1;
    __hip_bfloat16* dst = blockIdx.z ? W2t : W1t;
    __shared__ float t[32][33];
    const int bi = blockIdx.x * 32, bj = blockIdx.y * 32;
    #pragma unroll
    for (int k = 0; k < 4; ++k)
        t[threadIdx.y + 8*k][threadIdx.x] = src[(size_t)(bi + threadIdx.y + 8*k) * MW + bj + threadIdx.x];
    __syncthreads();
    #pragma unroll
    for (int k = 0; k < 4; ++k)
        dst[(size_t)(bj + threadIdx.y + 8*k) * MW + bi + threadIdx.x] =
            __float2bfloat16(t[threadIdx.x][threadIdx.y + 8*k]);
}

// ---------------------------------------------------------------------------
// Kernel 0b: 64x32 -> 32x64 transposes to bf16 (Wqkv and x)
// ---------------------------------------------------------------------------
__global__ __launch_bounds__(256) void k_prep2(
    const float* __restrict__ x,
    const float* __restrict__ Wq, const float* __restrict__ Wk, const float* __restrict__ Wv,
    __hip_bfloat16* __restrict__ xb, __hip_bfloat16* __restrict__ Wqkvt)
{
    const int job = blockIdx.x;
    const int tx = threadIdx.x & 31, ty = threadIdx.x >> 5;
    const float* src;
    size_t sstride;
    __hip_bfloat16* dst;
    if (job < 24) {
        int mtx = job >> 3, h = job & 7;
        const float* Wm = mtx == 0 ? Wq : (mtx == 1 ? Wk : Wv);
        src = Wm + (size_t)h * D_IN * NF;
        sstride = NF;
        dst = Wqkvt + (size_t)job * NF * D_IN;
    } else {
        int i = job - 24;
        int n = i / NSTRIP, lt = i % NSTRIP;
        src = x + (size_t)n * D_IN * L_TOT + lt * 32;
        sstride = L_TOT;
        dst = xb + ((size_t)n * L_TOT + lt * 32) * D_IN;
    }
    __shared__ float t[64][33];
    #pragma unroll
    for (int k = 0; k < 8; ++k)
        t[ty + 8 * k][tx] = src[(size_t)(ty + 8 * k) * sstride + tx];
    __syncthreads();
    #pragma unroll
    for (int k = 0; k < 4; ++k) {
        int col = ty + 8 * k;
        #pragma unroll
        for (int j = 0; j < 2; ++j)
            dst[(size_t)col * D_IN + tx + 32 * j] = __float2bfloat16(t[tx + 32 * j][col]);
    }
}

// ---------------------------------------------------------------------------
// Kernel 1 (MFMA proj): C[f][l] = Wt[h][f][:] . xb[l][:], +bias, InstanceNorm
// over f (register-local + one shfl), ReLU -> Qb/Kb [l][f], Vt [f][m].
// block = 256 (4 waves = 4 heads), grid = (72 ltiles, 2 n, 2 head-groups)
// ---------------------------------------------------------------------------
__global__ __launch_bounds__(256) void k_proj(
    const __hip_bfloat16* __restrict__ xb, const __hip_bfloat16* __restrict__ Wqkvt,
    const float* __restrict__ bq, const float* __restrict__ bk, const float* __restrict__ bv,
    __hip_bfloat16* __restrict__ Qo, __hip_bfloat16* __restrict__ Ko,
    __hip_bfloat16* __restrict__ Vt)
{
    const int ltile = blockIdx.x;
    const int n = blockIdx.y;
    const int h = blockIdx.z * 4 + (threadIdx.x >> 6);
    const int l0 = ltile * 32;
    const int lane = threadIdx.x & 63;
    const int c = lane & 31, hi = lane >> 5;
    const int hn = h * NB + n;

    const bf16x8* xp = reinterpret_cast<const bf16x8*>(
        xb + ((size_t)n * L_TOT + l0 + c) * D_IN);
    bf16x8 xf[4];
    #pragma unroll
    for (int t = 0; t < 4; ++t) xf[t] = xp[2 * t + hi];

    const float* bs[3] = {bq, bk, bv};

    #pragma unroll
    for (int mtx = 0; mtx < 3; ++mtx) {
        const bf16x8* wp = reinterpret_cast<const bf16x8*>(
            Wqkvt + ((size_t)(mtx * NH + h) * NF + c) * D_IN);
        f32x16 acc = {};
        #pragma unroll
        for (int t = 0; t < 4; ++t)
            acc = __builtin_amdgcn_mfma_f32_32x32x16_bf16(wp[2 * t + hi], xf[t], acc, 0, 0, 0);

        float bb[16];
        #pragma unroll
        for (int g = 0; g < 4; ++g) {
            float4 t4 = *reinterpret_cast<const float4*>(&bs[mtx][h * NF + 8 * g + 4 * hi]);
            bb[4 * g + 0] = t4.x; bb[4 * g + 1] = t4.y;
            bb[4 * g + 2] = t4.z; bb[4 * g + 3] = t4.w;
        }

        float v[16], s = 0.f, s2 = 0.f;
        #pragma unroll
        for (int r = 0; r < 16; ++r) {
            v[r] = acc[r] + bb[r];
            s += v[r]; s2 += v[r] * v[r];
        }
        s  += __shfl_xor(s, 32, 64);
        s2 += __shfl_xor(s2, 32, 64);
        float mu = s * (1.f / 32);
        float rstd = rsqrtf(s2 * (1.f / 32) - mu * mu + EPSV);
        float y[16];
        #pragma unroll
        for (int r = 0; r < 16; ++r) y[r] = fmaxf((v[r] - mu) * rstd, 0.f);

        if (mtx == 2) {
            #pragma unroll
            for (int r = 0; r < 16; ++r) {
                int f = (r & 3) + 8 * (r >> 2) + 4 * hi;
                Vt[((size_t)(hn * NSTRIP + ltile) * NF + f) * 32 + c] = __float2bfloat16(y[r]);
            }
        } else {
            if (mtx == 0) {
                #pragma unroll
                for (int r = 0; r < 16; ++r) y[r] *= SCALE;
            }
            uint32_t pk[8];
            #pragma unroll
            for (int q = 0; q < 8; ++q) pk[q] = pack_bf16(y[2 * q], y[2 * q + 1]);
            uint32_t rr[4];
            #pragma unroll
            for (int j = 0; j < 4; ++j)
                rr[j] = (uint32_t)__shfl_xor((int)(hi ? pk[j] : pk[4 + j]), 32, 64);
            uint32_t row[8];
            if (hi == 0) {
                row[0] = pk[0]; row[1] = pk[1]; row[2] = rr[0]; row[3] = rr[1];
                row[4] = pk[2]; row[5] = pk[3]; row[6] = rr[2]; row[7] = rr[3];
            } else {
                row[0] = rr[0]; row[1] = rr[1]; row[2] = pk[4]; row[3] = pk[5];
                row[4] = rr[2]; row[5] = rr[3]; row[6] = pk[6]; row[7] = pk[7];
            }
            __hip_bfloat16* dst = (mtx == 0 ? Qo : Ko)
                + ((size_t)hn * L_TOT + l0 + c) * NF + hi * 16;
            reinterpret_cast<uint4*>(dst)[0] = make_uint4(row[0], row[1], row[2], row[3]);
            reinterpret_cast<uint4*>(dst)[1] = make_uint4(row[4], row[5], row[6], row[7]);
        }
    }
}

// ---------------------------------------------------------------------------
// Kernel 2: column softmax stats. S^T = K @ Q^T per 32-m strip via MFMA.
// block = 256 (4 indep waves), grid = (18, 16 hn, CHS)
// ---------------------------------------------------------------------------
__global__ __launch_bounds__(256) void k_stats(
    const __hip_bfloat16* __restrict__ Qb, const __hip_bfloat16* __restrict__ Kb,
    float* __restrict__ zpart)
{
    const int w = threadIdx.x >> 6;
    const int strip = blockIdx.x * 4 + w;
    const int hn = blockIdx.y;
    const int chunk = blockIdx.z;
    const int lane = threadIdx.x & 63;
    const int c = lane & 31, hi = lane >> 5;

    const bf16x8* kp = reinterpret_cast<const bf16x8*>(
        Kb + ((size_t)hn * L_TOT + strip * 32 + c) * NF);
    const bf16x8 ka0 = kp[hi];
    const bf16x8 ka1 = kp[2 + hi];

    float Zr[16];
    #pragma unroll
    for (int r = 0; r < 16; ++r) Zr[r] = 0.f;

    for (int it = 0; it < (L_TOT / 32) / CHS; ++it) {
        const int l0 = (chunk * ((L_TOT / 32) / CHS) + it) * 32;
        const bf16x8* qp = reinterpret_cast<const bf16x8*>(
            Qb + ((size_t)hn * L_TOT + l0 + c) * NF);
        bf16x8 qb0 = qp[hi];
        bf16x8 qb1 = qp[2 + hi];
        f32x16 s16 = {};
        s16 = __builtin_amdgcn_mfma_f32_32x32x16_bf16(ka0, qb0, s16, 0, 0, 0);
        s16 = __builtin_amdgcn_mfma_f32_32x32x16_bf16(ka1, qb1, s16, 0, 0, 0);
        #pragma unroll
        for (int r = 0; r < 16; ++r) Zr[r] += __expf(s16[r] - SHIFT);
    }
    #pragma unroll
    for (int r = 0; r < 16; ++r) {
        #pragma unroll
        for (int o = 16; o >= 1; o >>= 1) Zr[r] += __shfl_xor(Zr[r], o, 64);
    }
    if (c == 0) {
        float4* zp = reinterpret_cast<float4*>(
            zpart + ((size_t)chunk * 16 + hn) * L_TOT + strip * 32 + hi * 16);
        zp[0] = make_float4(Zr[0], Zr[1], Zr[2], Zr[3]);
        zp[1] = make_float4(Zr[4], Zr[5], Zr[6], Zr[7]);
        zp[2] = make_float4(Zr[8], Zr[9], Zr[10], Zr[11]);
        zp[3] = make_float4(Zr[12], Zr[13], Zr[14], Zr[15]);
    }
}

// Combine chunks -> lse (same permuted layout)
__global__ __launch_bounds__(256) void k_finish(
    const float* __restrict__ zpart, float* __restrict__ lse_p)
{
    const int idx = blockIdx.x * 256 + threadIdx.x;
    float Z = 0.f;
    #pragma unroll
    for (int cc = 0; cc < CHS; ++cc) Z += zpart[(size_t)cc * 16 * L_TOT + idx];
    lse_p[idx] = SHIFT + logf(Z);
}

// ---------------------------------------------------------------------------
// Kernel 3: apply. One block per (ltile, hn); the block's 4 waves split the
// m-loop (18 strips each) and LDS-reduce their f32x16 partials.
// block = 256, grid = (72, 16)
// ---------------------------------------------------------------------------
__global__ __launch_bounds__(256) void k_apply(
    const __hip_bfloat16* __restrict__ Qb, const __hip_bfloat16* __restrict__ Kb,
    const __hip_bfloat16* __restrict__ Vt, const float* __restrict__ lse_p,
    float* __restrict__ partA)
{
    const int w = threadIdx.x >> 6;          // m-range index 0..3
    const int ltile = blockIdx.x;
    const int l0 = ltile * 32;
    const int hn = blockIdx.y;
    const int lane = threadIdx.x & 63;
    const int c = lane & 31, hi = lane >> 5;

    const bf16x8* qp = reinterpret_cast<const bf16x8*>(
        Qb + ((size_t)hn * L_TOT + l0 + c) * NF);
    const bf16x8 qb0 = qp[hi];
    const bf16x8 qb1 = qp[2 + hi];

    f32x16 acc = {};

    #pragma unroll 2
    for (int it = 0; it < NSTRIP / 4; ++it) {
        const int st = w * (NSTRIP / 4) + it;
        const bf16x8* kp = reinterpret_cast<const bf16x8*>(
            Kb + ((size_t)hn * L_TOT + st * 32 + c) * NF);
        f32x16 s16 = {};
        s16 = __builtin_amdgcn_mfma_f32_32x32x16_bf16(kp[hi], qb0, s16, 0, 0, 0);
        s16 = __builtin_amdgcn_mfma_f32_32x32x16_bf16(kp[2 + hi], qb1, s16, 0, 0, 0);

        const float4* lp = reinterpret_cast<const float4*>(
            lse_p + (size_t)hn * L_TOT + st * 32 + hi * 16);
        float lv[16];
        #pragma unroll
        for (int q = 0; q < 4; ++q) {
            float4 t = lp[q];
            lv[4 * q + 0] = t.x; lv[4 * q + 1] = t.y;
            lv[4 * q + 2] = t.z; lv[4 * q + 3] = t.w;
        }
        float p[16];
        #pragma unroll
        for (int r = 0; r < 16; ++r) p[r] = __expf(s16[r] - lv[r]);

        uint32_t wp[8];
        #pragma unroll
        for (int q = 0; q < 8; ++q) wp[q] = pack_bf16(p[2 * q], p[2 * q + 1]);

        uint32_t sendA = hi ? wp[0] : wp[2];
        uint32_t sendB = hi ? wp[1] : wp[3];
        uint32_t rA = (uint32_t)__shfl_xor((int)sendA, 32, 64);
        uint32_t rB = (uint32_t)__shfl_xor((int)sendB, 32, 64);
        U32x4BF fragP0;
        fragP0.u[0] = hi ? rA    : wp[0];
        fragP0.u[1] = hi ? rB    : wp[1];
        fragP0.u[2] = hi ? wp[2] : rA;
        fragP0.u[3] = hi ? wp[3] : rB;
        uint32_t sendC = hi ? wp[4] : wp[6];
        uint32_t sendD = hi ? wp[5] : wp[7];
        uint32_t rC = (uint32_t)__shfl_xor((int)sendC, 32, 64);
        uint32_t rD = (uint32_t)__shfl_xor((int)sendD, 32, 64);
        U32x4BF fragP1;
        fragP1.u[0] = hi ? rC    : wp[4];
        fragP1.u[1] = hi ? rD    : wp[5];
        fragP1.u[2] = hi ? wp[6] : rC;
        fragP1.u[3] = hi ? wp[7] : rD;

        const bf16x8* vp = reinterpret_cast<const bf16x8*>(
            Vt + ((size_t)(hn * NSTRIP + st) * NF + c) * 32);
        acc = __builtin_amdgcn_mfma_f32_32x32x16_bf16(fragP0.v, vp[hi], acc, 0, 0, 0);
        acc = __builtin_amdgcn_mfma_f32_32x32x16_bf16(fragP1.v, vp[2 + hi], acc, 0, 0, 0);
    }

    // LDS reduction of the 4 per-wave partials (lane-major: conflict-free)
    __shared__ float red[4][16][64];
    #pragma unroll
    for (int r = 0; r < 16; ++r) red[w][r][lane] = acc[r];
    __syncthreads();

    const int n = hn & 1, h = hn >> 1;
    float* outp = partA + ((size_t)(n * L_TOT + l0)) * MW + h * NF + c;
    #pragma unroll
    for (int j = 0; j < 4; ++j) {
        const int r = 4 * w + j;              // this wave finalizes C-regs 4w..4w+3
        float sv = red[0][r][lane] + red[1][r][lane] + red[2][r][lane] + red[3][r][lane];
        const int row = (r & 3) + 8 * (r >> 2) + 4 * hi;   // = j + 8w + 4hi
        outp[(size_t)row * MW] = sv;
    }
}

// ---------------------------------------------------------------------------
// Kernel 4 (MFMA MLP): m=relu(relu(h@W1+b1)@W2+b2);
//   o = gamma*inorm(m+h)+beta; out[n,c,l].
// block = 512 (8 waves x 32-col groups), 32 rows/block, grid = 144
// ---------------------------------------------------------------------------
__global__ __launch_bounds__(512) void k_mlp(
    const float* __restrict__ partA,
    const __hip_bfloat16* __restrict__ W1t, const float* __restrict__ b1,
    const __hip_bfloat16* __restrict__ W2t, const float* __restrict__ b2,
    const float* __restrict__ gamma, const float* __restrict__ beta,
    float* __restrict__ out)
{
    const int blk = blockIdx.x;
    const int n  = blk / (L_TOT / RT);
    const int l0 = (blk % (L_TOT / RT)) * RT;
    const int tid = threadIdx.x;
    const int w = tid >> 6, lane = tid & 63;
    const int c = lane & 31, hi = lane >> 5;
    const int n0 = w * 32;

    __shared__ __align__(16) char smem[67584];
    float (*hsf)[MW] = reinterpret_cast<float (*)[MW]>(smem);
    __hip_bfloat16 (*hA)[264]  = reinterpret_cast<__hip_bfloat16 (*)[264]>(smem + 32768);
    __hip_bfloat16 (*msb)[264] = reinterpret_cast<__hip_bfloat16 (*)[264]>(smem + 49664);
    float (*ys)[MW] = reinterpret_cast<float (*)[MW]>(smem + 32768);
    float (*rs)[4]  = reinterpret_cast<float (*)[4]>(smem + 66560);
    float (*rs2)[4] = reinterpret_cast<float (*)[4]>(smem + 67072);

    for (int idx = tid; idx < RT * MW; idx += 512) {
        int r = idx >> 8, i = idx & 255;
        float v = partA[((size_t)n * L_TOT + l0 + r) * MW + i];
        hsf[r][i] = v;
        hA[r][i] = __float2bfloat16(v);
    }
    __syncthreads();

    // ---- layer 1 ----
    const float bb1 = b1[n0 + c];
    bf16x8 B1[16];
    #pragma unroll
    for (int k0 = 0; k0 < 16; ++k0)
        B1[k0] = *reinterpret_cast<const bf16x8*>(W1t + (size_t)(n0 + c) * MW + k0 * 16 + hi * 8);
    f32x16 acc = {};
    #pragma unroll
    for (int k0 = 0; k0 < 16; ++k0) {
        bf16x8 a = *reinterpret_cast<const bf16x8*>(&hA[c][k0 * 16 + hi * 8]);
        acc = __builtin_amdgcn_mfma_f32_32x32x16_bf16(a, B1[k0], acc, 0, 0, 0);
    }
    #pragma unroll
    for (int r = 0; r < 16; ++r) {
        int row = (r & 3) + 8 * (r >> 2) + 4 * hi;
        msb[row][n0 + c] = __float2bfloat16(fmaxf(acc[r] + bb1, 0.f));
    }
    __syncthreads();

    // ---- layer 2 + residual ----
    const float bb2 = b2[n0 + c];
    bf16x8 B2[16];
    #pragma unroll
    for (int k0 = 0; k0 < 16; ++k0)
        B2[k0] = *reinterpret_cast<const bf16x8*>(W2t + (size_t)(n0 + c) * MW + k0 * 16 + hi * 8);
    f32x16 acc2 = {};
    #pragma unroll
    for (int k0 = 0; k0 < 16; ++k0) {
        bf16x8 a = *reinterpret_cast<const bf16x8*>(&msb[c][k0 * 16 + hi * 8]);
        acc2 = __builtin_amdgcn_mfma_f32_32x32x16_bf16(a, B2[k0], acc2, 0, 0, 0);
    }
    float yv[16];
    #pragma unroll
    for (int r = 0; r < 16; ++r) {
        int row = (r & 3) + 8 * (r >> 2) + 4 * hi;
        yv[r] = fmaxf(acc2[r] + bb2, 0.f) + hsf[row][n0 + c];
    }
    __syncthreads();
    #pragma unroll
    for (int r = 0; r < 16; ++r) {
        int row = (r & 3) + 8 * (r >> 2) + 4 * hi;
        ys[row][n0 + c] = yv[r];
    }
    __syncthreads();

    // ---- instance norm over 256 channels per row + transposed store ----
    const int col = tid & 255;
    const int half = tid >> 8;
    const int wid = (tid >> 6) & 3;
    float vv[16];
    #pragma unroll
    for (int r = 0; r < 16; ++r) {
        float v = ys[half * 16 + r][col];
        vv[r] = v;
        float s = v, s2 = v * v;
        #pragma unroll
        for (int o = 32; o >= 1; o >>= 1) { s += __shfl_xor(s, o, 64); s2 += __shfl_xor(s2, o, 64); }
        if (lane == 0) { rs[half * 16 + r][wid] = s; rs2[half * 16 + r][wid] = s2; }
    }
    __syncthreads();
    const float g = gamma[col], be = beta[col];
    float ov[16];
    #pragma unroll
    for (int r = 0; r < 16; ++r) {
        int row = half * 16 + r;
        float s  = rs[row][0]  + rs[row][1]  + rs[row][2]  + rs[row][3];
        float s2 = rs2[row][0] + rs2[row][1] + rs2[row][2] + rs2[row][3];
        float mu  = s  * (1.f / MW);
        float var = s2 * (1.f / MW) - mu * mu;
        ov[r] = g * ((vv[r] - mu) * rsqrtf(var + EPSV)) + be;
    }
    float* ob = out + ((size_t)n * MW + col) * L_TOT + l0 + half * 16;
    #pragma unroll
    for (int q = 0; q < 4; ++q)
        reinterpret_cast<float4*>(ob)[q] =
            make_float4(ov[4 * q], ov[4 * q + 1], ov[4 * q + 2], ov[4 * q + 3]);
}

// ---------------------------------------------------------------------------
extern "C" void kernel_launch(void* const* d_in, const int* in_sizes, int n_in,
                              void* d_out, int out_size, void* d_ws, size_t ws_size,
                              hipStream_t stream) {
    const float* x  = (const float*)d_in[0];
    const float* Wq = (const float*)d_in[1];
    const float* bq = (const float*)d_in[2];
    const float* Wk = (const float*)d_in[3];
    const float* bk = (const float*)d_in[4];
    const float* Wv = (const float*)d_in[5];
    const float* bv = (const float*)d_in[6];
    const float* W1 = (const float*)d_in[7];
    const float* b1 = (const float*)d_in[8];
    const float* W2 = (const float*)d_in[9];
    const float* b2 = (const float*)d_in[10];
    const float* gm = (const float*)d_in[11];
    const float* bt = (const float*)d_in[12];
    float* out = (float*)d_out;

    const size_t QKVE = (size_t)16 * L_TOT * NF;   // 1,179,648 bf16 elems each
    const size_t XBE  = (size_t)NB * L_TOT * D_IN; // 294,912
    const size_t WQE  = (size_t)3 * NH * NF * D_IN;// 49,152
    const size_t WTE  = (size_t)MW * MW;           // 65,536 per matrix
    const size_t ZN = (size_t)CHS * 16 * L_TOT;
    const size_t LN = (size_t)16 * L_TOT;

    __hip_bfloat16* Qb = (__hip_bfloat16*)d_ws;
    __hip_bfloat16* Kb = Qb + QKVE;
    __hip_bfloat16* Vt = Kb + QKVE;
    __hip_bfloat16* xb = Vt + QKVE;
    __hip_bfloat16* Wqkvt = xb + XBE;
    __hip_bfloat16* W1t = Wqkvt + WQE;
    __hip_bfloat16* W2t = W1t + WTE;
    float* zpart = (float*)(W2t + WTE);
    float* lse_p = zpart + ZN;
    float* partA = lse_p + LN;

    k_prep<<<dim3(8, 8, 2), dim3(32, 8), 0, stream>>>(W1, W2, W1t, W2t);
    k_prep2<<<dim3(24 + NB * NSTRIP), dim3(256), 0, stream>>>(x, Wq, Wk, Wv, xb, Wqkvt);
    k_proj<<<dim3(NSTRIP, NB, 2), dim3(256), 0, stream>>>(
        xb, Wqkvt, bq, bk, bv, Qb, Kb, Vt);
    k_stats<<<dim3(NSTRIP / 4, 16, CHS), dim3(256), 0, stream>>>(Qb, Kb, zpart);
    k_finish<<<dim3(16 * L_TOT / 256), dim3(256), 0, stream>>>(zpart, lse_p);
    k_apply<<<dim3(NSTRIP, 16), dim3(256), 0, stream>>>(
        Qb, Kb, Vt, lse_p, partA);
    k_mlp<<<dim3(NB * (L_TOT / RT)), dim3(512), 0, stream>>>(
        partA, W1t, b1, W2t, b2, gm, bt, out);
}

// Round 8
// 122.920 us; speedup vs baseline: 1.1682x; 1.0711x over previous
//
#include <hip/hip_runtime.h>
#include <hip/hip_bf16.h>
#include <stdint.h>

// Problem constants
#define L_TOT 2304   // 48*48
#define D_IN  64
#define NF    32     // features per head
#define NH    8      // heads
#define NB    2      // batch
#define MW    256    // MLP width = NH*NF
#define CHS   8      // l-chunks for stats pass
#define NSTRIP (L_TOT/32)   // 72 m-strips
#define RT    32     // rows per k_mlp block

constexpr float EPSV  = 1e-5f;
// Q pre-scale: log2(e)/sqrt(32). Scores land in log2 domain; s in [0, ~8.2],
// 2^s <= ~290, Z <= 7e5 -> no shift needed (Q,K >= 0 after ReLU).
constexpr float SCALE2 = 0.2550351f;

typedef __bf16  bf16x8  __attribute__((ext_vector_type(8)));
typedef float   f32x16  __attribute__((ext_vector_type(16)));

union U32x4BF { uint32_t u[4]; bf16x8 v; };

// Pack two f32 -> one u32 of two bf16 (element 0 = low halfword = a).
static __device__ __forceinline__ uint32_t pack_bf16(float a, float b) {
    union { __bf16 h[2]; uint32_t u; } r;
    r.h[0] = (__bf16)a;
    r.h[1] = (__bf16)b;
    return r.u;
}

// ---------------------------------------------------------------------------
// Kernel 0a: transpose W1,W2 -> bf16 [out][in] for MLP MFMA B-operands
// ---------------------------------------------------------------------------
__global__ void k_prep(const float* __restrict__ W1, const float* __restrict__ W2,
                       __hip_bfloat16* __restrict__ W1t, __hip_bfloat16* __restrict__ W2t)
{
    const float* src = blockIdx.z ? W2 : W1;
    __hip_bfloat16* dst = blockIdx.z ? W2t : W1t;
    __shared__ float t[32][33];
    const int bi = blockIdx.x * 32, bj = blockIdx.y * 32;
    #pragma unroll
    for (int k = 0; k < 4; ++k)
        t[threadIdx.y + 8*k][threadIdx.x] = src[(size_t)(bi + threadIdx.y + 8*k) * MW + bj + threadIdx.x];
    __syncthreads();
    #pragma unroll
    for (int k = 0; k < 4; ++k)
        dst[(size_t)(bj + threadIdx.y + 8*k) * MW + bi + threadIdx.x] =
            __float2bfloat16(t[threadIdx.x][threadIdx.y + 8*k]);
}

// ---------------------------------------------------------------------------
// Kernel 0b: 64x32 -> 32x64 transposes to bf16 (Wqkv and x)
// ---------------------------------------------------------------------------
__global__ __launch_bounds__(256) void k_prep2(
    const float* __restrict__ x,
    const float* __restrict__ Wq, const float* __restrict__ Wk, const float* __restrict__ Wv,
    __hip_bfloat16* __restrict__ xb, __hip_bfloat16* __restrict__ Wqkvt)
{
    const int job = blockIdx.x;
    const int tx = threadIdx.x & 31, ty = threadIdx.x >> 5;
    const float* src;
    size_t sstride;
    __hip_bfloat16* dst;
    if (job < 24) {
        int mtx = job >> 3, h = job & 7;
        const float* Wm = mtx == 0 ? Wq : (mtx == 1 ? Wk : Wv);
        src = Wm + (size_t)h * D_IN * NF;
        sstride = NF;
        dst = Wqkvt + (size_t)job * NF * D_IN;
    } else {
        int i = job - 24;
        int n = i / NSTRIP, lt = i % NSTRIP;
        src = x + (size_t)n * D_IN * L_TOT + lt * 32;
        sstride = L_TOT;
        dst = xb + ((size_t)n * L_TOT + lt * 32) * D_IN;
    }
    __shared__ float t[64][33];
    #pragma unroll
    for (int k = 0; k < 8; ++k)
        t[ty + 8 * k][tx] = src[(size_t)(ty + 8 * k) * sstride + tx];
    __syncthreads();
    #pragma unroll
    for (int k = 0; k < 4; ++k) {
        int col = ty + 8 * k;
        #pragma unroll
        for (int j = 0; j < 2; ++j)
            dst[(size_t)col * D_IN + tx + 32 * j] = __float2bfloat16(t[tx + 32 * j][col]);
    }
}

// ---------------------------------------------------------------------------
// Kernel 1 (MFMA proj): C[f][l] = Wt[h][f][:] . xb[l][:], +bias, InstanceNorm
// over f (register-local + one shfl), ReLU -> Qb/Kb [l][f], Vt [f][m].
// block = 256 (4 waves = 4 heads), grid = (72 ltiles, 2 n, 2 head-groups)
// ---------------------------------------------------------------------------
__global__ __launch_bounds__(256) void k_proj(
    const __hip_bfloat16* __restrict__ xb, const __hip_bfloat16* __restrict__ Wqkvt,
    const float* __restrict__ bq, const float* __restrict__ bk, const float* __restrict__ bv,
    __hip_bfloat16* __restrict__ Qo, __hip_bfloat16* __restrict__ Ko,
    __hip_bfloat16* __restrict__ Vt)
{
    const int ltile = blockIdx.x;
    const int n = blockIdx.y;
    const int h = blockIdx.z * 4 + (threadIdx.x >> 6);
    const int l0 = ltile * 32;
    const int lane = threadIdx.x & 63;
    const int c = lane & 31, hi = lane >> 5;
    const int hn = h * NB + n;

    const bf16x8* xp = reinterpret_cast<const bf16x8*>(
        xb + ((size_t)n * L_TOT + l0 + c) * D_IN);
    bf16x8 xf[4];
    #pragma unroll
    for (int t = 0; t < 4; ++t) xf[t] = xp[2 * t + hi];

    const float* bs[3] = {bq, bk, bv};

    #pragma unroll
    for (int mtx = 0; mtx < 3; ++mtx) {
        const bf16x8* wp = reinterpret_cast<const bf16x8*>(
            Wqkvt + ((size_t)(mtx * NH + h) * NF + c) * D_IN);
        f32x16 acc = {};
        #pragma unroll
        for (int t = 0; t < 4; ++t)
            acc = __builtin_amdgcn_mfma_f32_32x32x16_bf16(wp[2 * t + hi], xf[t], acc, 0, 0, 0);

        float bb[16];
        #pragma unroll
        for (int g = 0; g < 4; ++g) {
            float4 t4 = *reinterpret_cast<const float4*>(&bs[mtx][h * NF + 8 * g + 4 * hi]);
            bb[4 * g + 0] = t4.x; bb[4 * g + 1] = t4.y;
            bb[4 * g + 2] = t4.z; bb[4 * g + 3] = t4.w;
        }

        float v[16], s = 0.f, s2 = 0.f;
        #pragma unroll
        for (int r = 0; r < 16; ++r) {
            v[r] = acc[r] + bb[r];
            s += v[r]; s2 += v[r] * v[r];
        }
        s  += __shfl_xor(s, 32, 64);
        s2 += __shfl_xor(s2, 32, 64);
        float mu = s * (1.f / 32);
        float rstd = rsqrtf(s2 * (1.f / 32) - mu * mu + EPSV);
        float y[16];
        #pragma unroll
        for (int r = 0; r < 16; ++r) y[r] = fmaxf((v[r] - mu) * rstd, 0.f);

        if (mtx == 2) {
            #pragma unroll
            for (int r = 0; r < 16; ++r) {
                int f = (r & 3) + 8 * (r >> 2) + 4 * hi;
                Vt[((size_t)(hn * NSTRIP + ltile) * NF + f) * 32 + c] = __float2bfloat16(y[r]);
            }
        } else {
            if (mtx == 0) {
                #pragma unroll
                for (int r = 0; r < 16; ++r) y[r] *= SCALE2;
            }
            uint32_t pk[8];
            #pragma unroll
            for (int q = 0; q < 8; ++q) pk[q] = pack_bf16(y[2 * q], y[2 * q + 1]);
            uint32_t rr[4];
            #pragma unroll
            for (int j = 0; j < 4; ++j)
                rr[j] = (uint32_t)__shfl_xor((int)(hi ? pk[j] : pk[4 + j]), 32, 64);
            uint32_t row[8];
            if (hi == 0) {
                row[0] = pk[0]; row[1] = pk[1]; row[2] = rr[0]; row[3] = rr[1];
                row[4] = pk[2]; row[5] = pk[3]; row[6] = rr[2]; row[7] = rr[3];
            } else {
                row[0] = rr[0]; row[1] = rr[1]; row[2] = pk[4]; row[3] = pk[5];
                row[4] = rr[2]; row[5] = rr[3]; row[6] = pk[6]; row[7] = pk[7];
            }
            __hip_bfloat16* dst = (mtx == 0 ? Qo : Ko)
                + ((size_t)hn * L_TOT + l0 + c) * NF + hi * 16;
            reinterpret_cast<uint4*>(dst)[0] = make_uint4(row[0], row[1], row[2], row[3]);
            reinterpret_cast<uint4*>(dst)[1] = make_uint4(row[4], row[5], row[6], row[7]);
        }
    }
}

// ---------------------------------------------------------------------------
// Kernel 2: column softmax stats. S^T = K @ Q^T per 32-m strip via MFMA.
// Z[m] = sum_l 2^s16. Stored permuted: zpart[chunk][hn][strip*32 + hi*16 + r]
// block = 256 (4 indep waves), grid = (18, 16 hn, CHS=8)
// ---------------------------------------------------------------------------
__global__ __launch_bounds__(256) void k_stats(
    const __hip_bfloat16* __restrict__ Qb, const __hip_bfloat16* __restrict__ Kb,
    float* __restrict__ zpart)
{
    const int w = threadIdx.x >> 6;
    const int strip = blockIdx.x * 4 + w;
    const int hn = blockIdx.y;
    const int chunk = blockIdx.z;
    const int lane = threadIdx.x & 63;
    const int c = lane & 31, hi = lane >> 5;

    const bf16x8* kp = reinterpret_cast<const bf16x8*>(
        Kb + ((size_t)hn * L_TOT + strip * 32 + c) * NF);
    const bf16x8 ka0 = kp[hi];
    const bf16x8 ka1 = kp[2 + hi];

    float Zr[16];
    #pragma unroll
    for (int r = 0; r < 16; ++r) Zr[r] = 0.f;

    for (int it = 0; it < (L_TOT / 32) / CHS; ++it) {
        const int l0 = (chunk * ((L_TOT / 32) / CHS) + it) * 32;
        const bf16x8* qp = reinterpret_cast<const bf16x8*>(
            Qb + ((size_t)hn * L_TOT + l0 + c) * NF);
        bf16x8 qb0 = qp[hi];
        bf16x8 qb1 = qp[2 + hi];
        f32x16 s16 = {};
        s16 = __builtin_amdgcn_mfma_f32_32x32x16_bf16(ka0, qb0, s16, 0, 0, 0);
        s16 = __builtin_amdgcn_mfma_f32_32x32x16_bf16(ka1, qb1, s16, 0, 0, 0);
        #pragma unroll
        for (int r = 0; r < 16; ++r) Zr[r] += exp2f(s16[r]);
    }
    #pragma unroll
    for (int r = 0; r < 16; ++r) {
        #pragma unroll
        for (int o = 16; o >= 1; o >>= 1) Zr[r] += __shfl_xor(Zr[r], o, 64);
    }
    if (c == 0) {
        float4* zp = reinterpret_cast<float4*>(
            zpart + ((size_t)chunk * 16 + hn) * L_TOT + strip * 32 + hi * 16);
        zp[0] = make_float4(Zr[0], Zr[1], Zr[2], Zr[3]);
        zp[1] = make_float4(Zr[4], Zr[5], Zr[6], Zr[7]);
        zp[2] = make_float4(Zr[8], Zr[9], Zr[10], Zr[11]);
        zp[3] = make_float4(Zr[12], Zr[13], Zr[14], Zr[15]);
    }
}

// Combine chunks -> zinv in NATURAL m order (un-permute on write)
__global__ __launch_bounds__(256) void k_finish(
    const float* __restrict__ zpart, float* __restrict__ zinv)
{
    const int idx = blockIdx.x * 256 + threadIdx.x;   // hn*L + perm(m)
    float Z = 0.f;
    #pragma unroll
    for (int cc = 0; cc < CHS; ++cc) Z += zpart[(size_t)cc * 16 * L_TOT + idx];
    const int p = idx & 31;
    const int hi = (p >> 4) & 1, r = p & 15;
    const int m_local = (r & 3) + 8 * (r >> 2) + 4 * hi;
    zinv[(idx & ~31) + m_local] = 1.f / Z;
}

// Fold zinv into V in place: Vt[hn][strip][f][m] *= zinv[hn][strip*32+m]
// grid = (72, 16), block = 256 (thread: one f, 4 consecutive m)
__global__ __launch_bounds__(256) void k_vscale(
    __hip_bfloat16* __restrict__ Vt, const float* __restrict__ zinv)
{
    const int strip = blockIdx.x, hn = blockIdx.y;
    const int f = threadIdx.x >> 3, mg = (threadIdx.x & 7) * 4;
    const float4 zl = *reinterpret_cast<const float4*>(
        zinv + (size_t)hn * L_TOT + strip * 32 + mg);
    __hip_bfloat16* p = Vt + ((size_t)(hn * NSTRIP + strip) * NF + f) * 32 + mg;
    uint2* p2 = reinterpret_cast<uint2*>(p);
    uint2 old = *p2;
    union { uint2 u2; __bf16 h[4]; } in, outv;
    in.u2 = old;
    outv.h[0] = (__bf16)((float)in.h[0] * zl.x);
    outv.h[1] = (__bf16)((float)in.h[1] * zl.y);
    outv.h[2] = (__bf16)((float)in.h[2] * zl.z);
    outv.h[3] = (__bf16)((float)in.h[3] * zl.w);
    *p2 = outv.u2;
}

// ---------------------------------------------------------------------------
// Kernel 3: apply. One block per (ltile, hn); 8 waves split the m-loop
// (9 strips each), LDS-reduce the f32x16 partials. p = 2^s16; V pre-scaled.
// block = 512, grid = (72, 16)
// ---------------------------------------------------------------------------
__global__ __launch_bounds__(512) void k_apply(
    const __hip_bfloat16* __restrict__ Qb, const __hip_bfloat16* __restrict__ Kb,
    const __hip_bfloat16* __restrict__ Vt,
    float* __restrict__ partA)
{
    const int w = threadIdx.x >> 6;          // m-range index 0..7
    const int ltile = blockIdx.x;
    const int l0 = ltile * 32;
    const int hn = blockIdx.y;
    const int lane = threadIdx.x & 63;
    const int c = lane & 31, hi = lane >> 5;

    const bf16x8* qp = reinterpret_cast<const bf16x8*>(
        Qb + ((size_t)hn * L_TOT + l0 + c) * NF);
    const bf16x8 qb0 = qp[hi];
    const bf16x8 qb1 = qp[2 + hi];

    f32x16 acc = {};

    #pragma unroll 3
    for (int it = 0; it < NSTRIP / 8; ++it) {
        const int st = w * (NSTRIP / 8) + it;
        const bf16x8* kp = reinterpret_cast<const bf16x8*>(
            Kb + ((size_t)hn * L_TOT + st * 32 + c) * NF);
        f32x16 s16 = {};
        s16 = __builtin_amdgcn_mfma_f32_32x32x16_bf16(kp[hi], qb0, s16, 0, 0, 0);
        s16 = __builtin_amdgcn_mfma_f32_32x32x16_bf16(kp[2 + hi], qb1, s16, 0, 0, 0);

        float p[16];
        #pragma unroll
        for (int r = 0; r < 16; ++r) p[r] = exp2f(s16[r]);

        uint32_t wp[8];
        #pragma unroll
        for (int q = 0; q < 8; ++q) wp[q] = pack_bf16(p[2 * q], p[2 * q + 1]);

        uint32_t sendA = hi ? wp[0] : wp[2];
        uint32_t sendB = hi ? wp[1] : wp[3];
        uint32_t rA = (uint32_t)__shfl_xor((int)sendA, 32, 64);
        uint32_t rB = (uint32_t)__shfl_xor((int)sendB, 32, 64);
        U32x4BF fragP0;
        fragP0.u[0] = hi ? rA    : wp[0];
        fragP0.u[1] = hi ? rB    : wp[1];
        fragP0.u[2] = hi ? wp[2] : rA;
        fragP0.u[3] = hi ? wp[3] : rB;
        uint32_t sendC = hi ? wp[4] : wp[6];
        uint32_t sendD = hi ? wp[5] : wp[7];
        uint32_t rC = (uint32_t)__shfl_xor((int)sendC, 32, 64);
        uint32_t rD = (uint32_t)__shfl_xor((int)sendD, 32, 64);
        U32x4BF fragP1;
        fragP1.u[0] = hi ? rC    : wp[4];
        fragP1.u[1] = hi ? rD    : wp[5];
        fragP1.u[2] = hi ? wp[6] : rC;
        fragP1.u[3] = hi ? wp[7] : rD;

        const bf16x8* vp = reinterpret_cast<const bf16x8*>(
            Vt + ((size_t)(hn * NSTRIP + st) * NF + c) * 32);
        acc = __builtin_amdgcn_mfma_f32_32x32x16_bf16(fragP0.v, vp[hi], acc, 0, 0, 0);
        acc = __builtin_amdgcn_mfma_f32_32x32x16_bf16(fragP1.v, vp[2 + hi], acc, 0, 0, 0);
    }

    // LDS reduction of the 8 per-wave partials (lane-major: conflict-free)
    __shared__ float red[8][16][64];
    #pragma unroll
    for (int r = 0; r < 16; ++r) red[w][r][lane] = acc[r];
    __syncthreads();

    const int n = hn & 1, h = hn >> 1;
    float* outp = partA + ((size_t)(n * L_TOT + l0)) * MW + h * NF + c;
    #pragma unroll
    for (int j = 0; j < 2; ++j) {
        const int r = 2 * w + j;              // this wave finalizes C-regs 2w..2w+1
        float sv = 0.f;
        #pragma unroll
        for (int k = 0; k < 8; ++k) sv += red[k][r][lane];
        const int row = (r & 3) + 8 * (r >> 2) + 4 * hi;
        outp[(size_t)row * MW] = sv;
    }
}

// ---------------------------------------------------------------------------
// Kernel 4 (MFMA MLP): m=relu(relu(h@W1+b1)@W2+b2);
//   o = gamma*inorm(m+h)+beta; out[n,c,l].
// block = 512 (8 waves x 32-col groups), 32 rows/block, grid = 144
// ---------------------------------------------------------------------------
__global__ __launch_bounds__(512) void k_mlp(
    const float* __restrict__ partA,
    const __hip_bfloat16* __restrict__ W1t, const float* __restrict__ b1,
    const __hip_bfloat16* __restrict__ W2t, const float* __restrict__ b2,
    const float* __restrict__ gamma, const float* __restrict__ beta,
    float* __restrict__ out)
{
    const int blk = blockIdx.x;
    const int n  = blk / (L_TOT / RT);
    const int l0 = (blk % (L_TOT / RT)) * RT;
    const int tid = threadIdx.x;
    const int w = tid >> 6, lane = tid & 63;
    const int c = lane & 31, hi = lane >> 5;
    const int n0 = w * 32;

    __shared__ __align__(16) char smem[67584];
    float (*hsf)[MW] = reinterpret_cast<float (*)[MW]>(smem);
    __hip_bfloat16 (*hA)[264]  = reinterpret_cast<__hip_bfloat16 (*)[264]>(smem + 32768);
    __hip_bfloat16 (*msb)[264] = reinterpret_cast<__hip_bfloat16 (*)[264]>(smem + 49664);
    float (*ys)[MW] = reinterpret_cast<float (*)[MW]>(smem + 32768);
    float (*rs)[4]  = reinterpret_cast<float (*)[4]>(smem + 66560);
    float (*rs2)[4] = reinterpret_cast<float (*)[4]>(smem + 67072);

    for (int idx = tid; idx < RT * MW; idx += 512) {
        int r = idx >> 8, i = idx & 255;
        float v = partA[((size_t)n * L_TOT + l0 + r) * MW + i];
        hsf[r][i] = v;
        hA[r][i] = __float2bfloat16(v);
    }
    __syncthreads();

    // ---- layer 1 ----
    const float bb1 = b1[n0 + c];
    bf16x8 B1[16];
    #pragma unroll
    for (int k0 = 0; k0 < 16; ++k0)
        B1[k0] = *reinterpret_cast<const bf16x8*>(W1t + (size_t)(n0 + c) * MW + k0 * 16 + hi * 8);
    f32x16 acc = {};
    #pragma unroll
    for (int k0 = 0; k0 < 16; ++k0) {
        bf16x8 a = *reinterpret_cast<const bf16x8*>(&hA[c][k0 * 16 + hi * 8]);
        acc = __builtin_amdgcn_mfma_f32_32x32x16_bf16(a, B1[k0], acc, 0, 0, 0);
    }
    #pragma unroll
    for (int r = 0; r < 16; ++r) {
        int row = (r & 3) + 8 * (r >> 2) + 4 * hi;
        msb[row][n0 + c] = __float2bfloat16(fmaxf(acc[r] + bb1, 0.f));
    }
    __syncthreads();

    // ---- layer 2 + residual ----
    const float bb2 = b2[n0 + c];
    bf16x8 B2[16];
    #pragma unroll
    for (int k0 = 0; k0 < 16; ++k0)
        B2[k0] = *reinterpret_cast<const bf16x8*>(W2t + (size_t)(n0 + c) * MW + k0 * 16 + hi * 8);
    f32x16 acc2 = {};
    #pragma unroll
    for (int k0 = 0; k0 < 16; ++k0) {
        bf16x8 a = *reinterpret_cast<const bf16x8*>(&msb[c][k0 * 16 + hi * 8]);
        acc2 = __builtin_amdgcn_mfma_f32_32x32x16_bf16(a, B2[k0], acc2, 0, 0, 0);
    }
    float yv[16];
    #pragma unroll
    for (int r = 0; r < 16; ++r) {
        int row = (r & 3) + 8 * (r >> 2) + 4 * hi;
        yv[r] = fmaxf(acc2[r] + bb2, 0.f) + hsf[row][n0 + c];
    }
    __syncthreads();
    #pragma unroll
    for (int r = 0; r < 16; ++r) {
        int row = (r & 3) + 8 * (r >> 2) + 4 * hi;
        ys[row][n0 + c] = yv[r];
    }
    __syncthreads();

    // ---- instance norm over 256 channels per row + transposed store ----
    const int col = tid & 255;
    const int half = tid >> 8;
    const int wid = (tid >> 6) & 3;
    float vv[16];
    #pragma unroll
    for (int r = 0; r < 16; ++r) {
        float v = ys[half * 16 + r][col];
        vv[r] = v;
        float s = v, s2 = v * v;
        #pragma unroll
        for (int o = 32; o >= 1; o >>= 1) { s += __shfl_xor(s, o, 64); s2 += __shfl_xor(s2, o, 64); }
        if (lane == 0) { rs[half * 16 + r][wid] = s; rs2[half * 16 + r][wid] = s2; }
    }
    __syncthreads();
    const float g = gamma[col], be = beta[col];
    float ov[16];
    #pragma unroll
    for (int r = 0; r < 16; ++r) {
        int row = half * 16 + r;
        float s  = rs[row][0]  + rs[row][1]  + rs[row][2]  + rs[row][3];
        float s2 = rs2[row][0] + rs2[row][1] + rs2[row][2] + rs2[row][3];
        float mu  = s  * (1.f / MW);
        float var = s2 * (1.f / MW) - mu * mu;
        ov[r] = g * ((vv[r] - mu) * rsqrtf(var + EPSV)) + be;
    }
    float* ob = out + ((size_t)n * MW + col) * L_TOT + l0 + half * 16;
    #pragma unroll
    for (int q = 0; q < 4; ++q)
        reinterpret_cast<float4*>(ob)[q] =
            make_float4(ov[4 * q], ov[4 * q + 1], ov[4 * q + 2], ov[4 * q + 3]);
}

// ---------------------------------------------------------------------------
extern "C" void kernel_launch(void* const* d_in, const int* in_sizes, int n_in,
                              void* d_out, int out_size, void* d_ws, size_t ws_size,
                              hipStream_t stream) {
    const float* x  = (const float*)d_in[0];
    const float* Wq = (const float*)d_in[1];
    const float* bq = (const float*)d_in[2];
    const float* Wk = (const float*)d_in[3];
    const float* bk = (const float*)d_in[4];
    const float* Wv = (const float*)d_in[5];
    const float* bv = (const float*)d_in[6];
    const float* W1 = (const float*)d_in[7];
    const float* b1 = (const float*)d_in[8];
    const float* W2 = (const float*)d_in[9];
    const float* b2 = (const float*)d_in[10];
    const float* gm = (const float*)d_in[11];
    const float* bt = (const float*)d_in[12];
    float* out = (float*)d_out;

    const size_t QKVE = (size_t)16 * L_TOT * NF;   // 1,179,648 bf16 elems each
    const size_t XBE  = (size_t)NB * L_TOT * D_IN; // 294,912
    const size_t WQE  = (size_t)3 * NH * NF * D_IN;// 49,152
    const size_t WTE  = (size_t)MW * MW;           // 65,536 per matrix
    const size_t ZN = (size_t)CHS * 16 * L_TOT;
    const size_t LN = (size_t)16 * L_TOT;

    __hip_bfloat16* Qb = (__hip_bfloat16*)d_ws;
    __hip_bfloat16* Kb = Qb + QKVE;
    __hip_bfloat16* Vt = Kb + QKVE;
    __hip_bfloat16* xb = Vt + QKVE;
    __hip_bfloat16* Wqkvt = xb + XBE;
    __hip_bfloat16* W1t = Wqkvt + WQE;
    __hip_bfloat16* W2t = W1t + WTE;
    float* zpart = (float*)(W2t + WTE);
    float* zinv  = zpart + ZN;
    float* partA = zinv + LN;

    k_prep<<<dim3(8, 8, 2), dim3(32, 8), 0, stream>>>(W1, W2, W1t, W2t);
    k_prep2<<<dim3(24 + NB * NSTRIP), dim3(256), 0, stream>>>(x, Wq, Wk, Wv, xb, Wqkvt);
    k_proj<<<dim3(NSTRIP, NB, 2), dim3(256), 0, stream>>>(
        xb, Wqkvt, bq, bk, bv, Qb, Kb, Vt);
    k_stats<<<dim3(NSTRIP / 4, 16, CHS), dim3(256), 0, stream>>>(Qb, Kb, zpart);
    k_finish<<<dim3(16 * L_TOT / 256), dim3(256), 0, stream>>>(zpart, zinv);
    k_vscale<<<dim3(NSTRIP, 16), dim3(256), 0, stream>>>(Vt, zinv);
    k_apply<<<dim3(NSTRIP, 16), dim3(512), 0, stream>>>(Qb, Kb, Vt, partA);
    k_mlp<<<dim3(NB * (L_TOT / RT)), dim3(512), 0, stream>>>(
        partA, W1t, b1, W2t, b2, gm, bt, out);
}

// Round 9
// 121.029 us; speedup vs baseline: 1.1864x; 1.0156x over previous
//
#include <hip/hip_runtime.h>
#include <hip/hip_bf16.h>
#include <stdint.h>

// Problem constants
#define L_TOT 2304   // 48*48
#define D_IN  64
#define NF    32     // features per head
#define NH    8      // heads
#define NB    2      // batch
#define MW    256    // MLP width = NH*NF
#define CHS   8      // l-chunks for stats pass
#define NSTRIP (L_TOT/32)   // 72 m-strips
#define RT    32     // rows per k_mlp block

constexpr float EPSV  = 1e-5f;
// Q pre-scale: log2(e)/sqrt(32). Scores in log2 domain; s in [0, ~8.2],
// 2^s <= ~290, Z <= 7e5 -> no max-shift needed (Q,K >= 0 after ReLU).
constexpr float SCALE2 = 0.2550351f;

typedef __bf16  bf16x8  __attribute__((ext_vector_type(8)));
typedef float   f32x16  __attribute__((ext_vector_type(16)));

union U32x4BF { uint32_t u[4]; bf16x8 v; };

// Pack two f32 -> one u32 of two bf16 (element 0 = low halfword = a).
static __device__ __forceinline__ uint32_t pack_bf16(float a, float b) {
    union { __bf16 h[2]; uint32_t u; } r;
    r.h[0] = (__bf16)a;
    r.h[1] = (__bf16)b;
    return r.u;
}

// ---------------------------------------------------------------------------
// Kernel 0 (merged prep): job-indexed transposes to bf16.
//   jobs 0..127  : W1/W2 32x32 transpose tiles -> W1t/W2t [out][in]
//   jobs 128..151: Wqkv[mtx][h][d][f] -> Wt[(mtx*8+h)][f][d]
//   jobs 152..295: x[n][d][l-tile] -> xb[n][l][d]
// block = 256, grid = 296
// ---------------------------------------------------------------------------
__global__ __launch_bounds__(256) void k_prep(
    const float* __restrict__ x,
    const float* __restrict__ Wq, const float* __restrict__ Wk, const float* __restrict__ Wv,
    const float* __restrict__ W1, const float* __restrict__ W2,
    __hip_bfloat16* __restrict__ xb, __hip_bfloat16* __restrict__ Wqkvt,
    __hip_bfloat16* __restrict__ W1t, __hip_bfloat16* __restrict__ W2t)
{
    const int job = blockIdx.x;
    const int tx = threadIdx.x & 31, ty = threadIdx.x >> 5;
    __shared__ float t[64][33];

    if (job < 128) {
        const int z = job >> 6;            // 0: W1, 1: W2
        const int tt = job & 63;
        const int bi = (tt >> 3) * 32, bj = (tt & 7) * 32;
        const float* src = z ? W2 : W1;
        __hip_bfloat16* dst = z ? W2t : W1t;
        #pragma unroll
        for (int k = 0; k < 4; ++k)
            t[ty + 8 * k][tx] = src[(size_t)(bi + ty + 8 * k) * MW + bj + tx];
        __syncthreads();
        #pragma unroll
        for (int k = 0; k < 4; ++k)
            dst[(size_t)(bj + ty + 8 * k) * MW + bi + tx] =
                __float2bfloat16(t[tx][ty + 8 * k]);
        return;
    }

    const float* src;
    size_t sstride;
    __hip_bfloat16* dst;
    if (job < 152) {
        int j = job - 128;                 // mtx*8 + h
        int mtx = j >> 3, h = j & 7;
        const float* Wm = mtx == 0 ? Wq : (mtx == 1 ? Wk : Wv);
        src = Wm + (size_t)h * D_IN * NF;
        sstride = NF;
        dst = Wqkvt + (size_t)j * NF * D_IN;
    } else {
        int i = job - 152;
        int n = i / NSTRIP, lt = i % NSTRIP;
        src = x + (size_t)n * D_IN * L_TOT + lt * 32;
        sstride = L_TOT;
        dst = xb + ((size_t)n * L_TOT + lt * 32) * D_IN;
    }
    #pragma unroll
    for (int k = 0; k < 8; ++k)
        t[ty + 8 * k][tx] = src[(size_t)(ty + 8 * k) * sstride + tx];
    __syncthreads();
    #pragma unroll
    for (int k = 0; k < 4; ++k) {
        int col = ty + 8 * k;
        #pragma unroll
        for (int j = 0; j < 2; ++j)
            dst[(size_t)col * D_IN + tx + 32 * j] = __float2bfloat16(t[tx + 32 * j][col]);
    }
}

// ---------------------------------------------------------------------------
// Kernel 1 (MFMA proj): C[f][l] = Wt[h][f][:] . xb[l][:], +bias, InstanceNorm
// over f (register-local + one shfl), ReLU -> Qb/Kb [l][f], Vt [f][m].
// block = 256 (4 waves = 4 heads), grid = (72 ltiles, 2 n, 2 head-groups)
// ---------------------------------------------------------------------------
__global__ __launch_bounds__(256) void k_proj(
    const __hip_bfloat16* __restrict__ xb, const __hip_bfloat16* __restrict__ Wqkvt,
    const float* __restrict__ bq, const float* __restrict__ bk, const float* __restrict__ bv,
    __hip_bfloat16* __restrict__ Qo, __hip_bfloat16* __restrict__ Ko,
    __hip_bfloat16* __restrict__ Vt)
{
    const int ltile = blockIdx.x;
    const int n = blockIdx.y;
    const int h = blockIdx.z * 4 + (threadIdx.x >> 6);
    const int l0 = ltile * 32;
    const int lane = threadIdx.x & 63;
    const int c = lane & 31, hi = lane >> 5;
    const int hn = h * NB + n;

    const bf16x8* xp = reinterpret_cast<const bf16x8*>(
        xb + ((size_t)n * L_TOT + l0 + c) * D_IN);
    bf16x8 xf[4];
    #pragma unroll
    for (int t = 0; t < 4; ++t) xf[t] = xp[2 * t + hi];

    const float* bs[3] = {bq, bk, bv};

    #pragma unroll
    for (int mtx = 0; mtx < 3; ++mtx) {
        const bf16x8* wp = reinterpret_cast<const bf16x8*>(
            Wqkvt + ((size_t)(mtx * NH + h) * NF + c) * D_IN);
        f32x16 acc = {};
        #pragma unroll
        for (int t = 0; t < 4; ++t)
            acc = __builtin_amdgcn_mfma_f32_32x32x16_bf16(wp[2 * t + hi], xf[t], acc, 0, 0, 0);

        float bb[16];
        #pragma unroll
        for (int g = 0; g < 4; ++g) {
            float4 t4 = *reinterpret_cast<const float4*>(&bs[mtx][h * NF + 8 * g + 4 * hi]);
            bb[4 * g + 0] = t4.x; bb[4 * g + 1] = t4.y;
            bb[4 * g + 2] = t4.z; bb[4 * g + 3] = t4.w;
        }

        float v[16], s = 0.f, s2 = 0.f;
        #pragma unroll
        for (int r = 0; r < 16; ++r) {
            v[r] = acc[r] + bb[r];
            s += v[r]; s2 += v[r] * v[r];
        }
        s  += __shfl_xor(s, 32, 64);
        s2 += __shfl_xor(s2, 32, 64);
        float mu = s * (1.f / 32);
        float rstd = rsqrtf(s2 * (1.f / 32) - mu * mu + EPSV);
        float y[16];
        #pragma unroll
        for (int r = 0; r < 16; ++r) y[r] = fmaxf((v[r] - mu) * rstd, 0.f);

        if (mtx == 2) {
            #pragma unroll
            for (int r = 0; r < 16; ++r) {
                int f = (r & 3) + 8 * (r >> 2) + 4 * hi;
                Vt[((size_t)(hn * NSTRIP + ltile) * NF + f) * 32 + c] = __float2bfloat16(y[r]);
            }
        } else {
            if (mtx == 0) {
                #pragma unroll
                for (int r = 0; r < 16; ++r) y[r] *= SCALE2;
            }
            uint32_t pk[8];
            #pragma unroll
            for (int q = 0; q < 8; ++q) pk[q] = pack_bf16(y[2 * q], y[2 * q + 1]);
            uint32_t rr[4];
            #pragma unroll
            for (int j = 0; j < 4; ++j)
                rr[j] = (uint32_t)__shfl_xor((int)(hi ? pk[j] : pk[4 + j]), 32, 64);
            uint32_t row[8];
            if (hi == 0) {
                row[0] = pk[0]; row[1] = pk[1]; row[2] = rr[0]; row[3] = rr[1];
                row[4] = pk[2]; row[5] = pk[3]; row[6] = rr[2]; row[7] = rr[3];
            } else {
                row[0] = rr[0]; row[1] = rr[1]; row[2] = pk[4]; row[3] = pk[5];
                row[4] = rr[2]; row[5] = rr[3]; row[6] = pk[6]; row[7] = pk[7];
            }
            __hip_bfloat16* dst = (mtx == 0 ? Qo : Ko)
                + ((size_t)hn * L_TOT + l0 + c) * NF + hi * 16;
            reinterpret_cast<uint4*>(dst)[0] = make_uint4(row[0], row[1], row[2], row[3]);
            reinterpret_cast<uint4*>(dst)[1] = make_uint4(row[4], row[5], row[6], row[7]);
        }
    }
}

// ---------------------------------------------------------------------------
// Kernel 2: column softmax stats. S^T = K @ Q^T per 32-m strip via MFMA.
// Z[m] = sum_l 2^s16. Stored permuted: zpart[chunk][hn][strip*32 + hi*16 + r]
// block = 256 (4 indep waves), grid = (18, 16 hn, CHS=8)
// ---------------------------------------------------------------------------
__global__ __launch_bounds__(256) void k_stats(
    const __hip_bfloat16* __restrict__ Qb, const __hip_bfloat16* __restrict__ Kb,
    float* __restrict__ zpart)
{
    const int w = threadIdx.x >> 6;
    const int strip = blockIdx.x * 4 + w;
    const int hn = blockIdx.y;
    const int chunk = blockIdx.z;
    const int lane = threadIdx.x & 63;
    const int c = lane & 31, hi = lane >> 5;

    const bf16x8* kp = reinterpret_cast<const bf16x8*>(
        Kb + ((size_t)hn * L_TOT + strip * 32 + c) * NF);
    const bf16x8 ka0 = kp[hi];
    const bf16x8 ka1 = kp[2 + hi];

    float Zr[16];
    #pragma unroll
    for (int r = 0; r < 16; ++r) Zr[r] = 0.f;

    for (int it = 0; it < (L_TOT / 32) / CHS; ++it) {
        const int l0 = (chunk * ((L_TOT / 32) / CHS) + it) * 32;
        const bf16x8* qp = reinterpret_cast<const bf16x8*>(
            Qb + ((size_t)hn * L_TOT + l0 + c) * NF);
        bf16x8 qb0 = qp[hi];
        bf16x8 qb1 = qp[2 + hi];
        f32x16 s16 = {};
        s16 = __builtin_amdgcn_mfma_f32_32x32x16_bf16(ka0, qb0, s16, 0, 0, 0);
        s16 = __builtin_amdgcn_mfma_f32_32x32x16_bf16(ka1, qb1, s16, 0, 0, 0);
        #pragma unroll
        for (int r = 0; r < 16; ++r) Zr[r] += exp2f(s16[r]);
    }
    #pragma unroll
    for (int r = 0; r < 16; ++r) {
        #pragma unroll
        for (int o = 16; o >= 1; o >>= 1) Zr[r] += __shfl_xor(Zr[r], o, 64);
    }
    if (c == 0) {
        float4* zp = reinterpret_cast<float4*>(
            zpart + ((size_t)chunk * 16 + hn) * L_TOT + strip * 32 + hi * 16);
        zp[0] = make_float4(Zr[0], Zr[1], Zr[2], Zr[3]);
        zp[1] = make_float4(Zr[4], Zr[5], Zr[6], Zr[7]);
        zp[2] = make_float4(Zr[8], Zr[9], Zr[10], Zr[11]);
        zp[3] = make_float4(Zr[12], Zr[13], Zr[14], Zr[15]);
    }
}

// ---------------------------------------------------------------------------
// Kernel 2b (merged finish+vscale): per (strip, hn): Z = sum of 8 chunk
// partials (permuted layout), un-permute, fold 1/Z into V in place.
// block = 256, grid = (72, 16)
// ---------------------------------------------------------------------------
__global__ __launch_bounds__(256) void k_norm(
    const float* __restrict__ zpart, __hip_bfloat16* __restrict__ Vt)
{
    const int strip = blockIdx.x, hn = blockIdx.y;
    __shared__ float zs[CHS][32];
    __shared__ float zinv_s[32];

    const int cc = threadIdx.x >> 5, p = threadIdx.x & 31;
    zs[cc][p] = zpart[((size_t)cc * 16 + hn) * L_TOT + strip * 32 + p];
    __syncthreads();
    if (threadIdx.x < 32) {
        const int p2 = threadIdx.x;
        float Z = 0.f;
        #pragma unroll
        for (int k = 0; k < CHS; ++k) Z += zs[k][p2];
        const int hi = p2 >> 4, r = p2 & 15;
        const int m_local = (r & 3) + 8 * (r >> 2) + 4 * hi;
        zinv_s[m_local] = 1.f / Z;
    }
    __syncthreads();

    const int f = threadIdx.x >> 3, mg = (threadIdx.x & 7) * 4;
    __hip_bfloat16* pv = Vt + ((size_t)(hn * NSTRIP + strip) * NF + f) * 32 + mg;
    uint2* p2v = reinterpret_cast<uint2*>(pv);
    union { uint2 u2; __bf16 h[4]; } in, outv;
    in.u2 = *p2v;
    outv.h[0] = (__bf16)((float)in.h[0] * zinv_s[mg + 0]);
    outv.h[1] = (__bf16)((float)in.h[1] * zinv_s[mg + 1]);
    outv.h[2] = (__bf16)((float)in.h[2] * zinv_s[mg + 2]);
    outv.h[3] = (__bf16)((float)in.h[3] * zinv_s[mg + 3]);
    *p2v = outv.u2;
}

// ---------------------------------------------------------------------------
// Kernel 3: apply. One block per (ltile, hn); 8 waves split the m-loop
// (9 strips each, dual acc chains), LDS-reduce the partials. p = 2^s16.
// block = 512, grid = (72, 16)
// ---------------------------------------------------------------------------
static __device__ __forceinline__ void apply_strip(
    int st, int hn, const bf16x8& qb0, const bf16x8& qb1,
    const __hip_bfloat16* __restrict__ Kb, const __hip_bfloat16* __restrict__ Vt,
    int c, int hi, f32x16& acc)
{
    const bf16x8* kp = reinterpret_cast<const bf16x8*>(
        Kb + ((size_t)hn * L_TOT + st * 32 + c) * NF);
    f32x16 s16 = {};
    s16 = __builtin_amdgcn_mfma_f32_32x32x16_bf16(kp[hi], qb0, s16, 0, 0, 0);
    s16 = __builtin_amdgcn_mfma_f32_32x32x16_bf16(kp[2 + hi], qb1, s16, 0, 0, 0);

    float p[16];
    #pragma unroll
    for (int r = 0; r < 16; ++r) p[r] = exp2f(s16[r]);

    uint32_t wp[8];
    #pragma unroll
    for (int q = 0; q < 8; ++q) wp[q] = pack_bf16(p[2 * q], p[2 * q + 1]);

    uint32_t sendA = hi ? wp[0] : wp[2];
    uint32_t sendB = hi ? wp[1] : wp[3];
    uint32_t rA = (uint32_t)__shfl_xor((int)sendA, 32, 64);
    uint32_t rB = (uint32_t)__shfl_xor((int)sendB, 32, 64);
    U32x4BF fragP0;
    fragP0.u[0] = hi ? rA    : wp[0];
    fragP0.u[1] = hi ? rB    : wp[1];
    fragP0.u[2] = hi ? wp[2] : rA;
    fragP0.u[3] = hi ? wp[3] : rB;
    uint32_t sendC = hi ? wp[4] : wp[6];
    uint32_t sendD = hi ? wp[5] : wp[7];
    uint32_t rC = (uint32_t)__shfl_xor((int)sendC, 32, 64);
    uint32_t rD = (uint32_t)__shfl_xor((int)sendD, 32, 64);
    U32x4BF fragP1;
    fragP1.u[0] = hi ? rC    : wp[4];
    fragP1.u[1] = hi ? rD    : wp[5];
    fragP1.u[2] = hi ? wp[6] : rC;
    fragP1.u[3] = hi ? wp[7] : rD;

    const bf16x8* vp = reinterpret_cast<const bf16x8*>(
        Vt + ((size_t)(hn * NSTRIP + st) * NF + c) * 32);
    acc = __builtin_amdgcn_mfma_f32_32x32x16_bf16(fragP0.v, vp[hi], acc, 0, 0, 0);
    acc = __builtin_amdgcn_mfma_f32_32x32x16_bf16(fragP1.v, vp[2 + hi], acc, 0, 0, 0);
}

__global__ __launch_bounds__(512) void k_apply(
    const __hip_bfloat16* __restrict__ Qb, const __hip_bfloat16* __restrict__ Kb,
    const __hip_bfloat16* __restrict__ Vt,
    float* __restrict__ partA)
{
    const int w = threadIdx.x >> 6;          // m-range index 0..7
    const int ltile = blockIdx.x;
    const int l0 = ltile * 32;
    const int hn = blockIdx.y;
    const int lane = threadIdx.x & 63;
    const int c = lane & 31, hi = lane >> 5;

    const bf16x8* qp = reinterpret_cast<const bf16x8*>(
        Qb + ((size_t)hn * L_TOT + l0 + c) * NF);
    const bf16x8 qb0 = qp[hi];
    const bf16x8 qb1 = qp[2 + hi];

    // dual accumulator chains over the wave's 9 strips (static indexing)
    f32x16 accA = {}, accB = {};
    const int sbase = w * (NSTRIP / 8);
    #pragma unroll
    for (int it2 = 0; it2 < 4; ++it2) {
        apply_strip(sbase + 2 * it2,     hn, qb0, qb1, Kb, Vt, c, hi, accA);
        apply_strip(sbase + 2 * it2 + 1, hn, qb0, qb1, Kb, Vt, c, hi, accB);
    }
    apply_strip(sbase + 8, hn, qb0, qb1, Kb, Vt, c, hi, accA);

    // LDS reduction of the 8 per-wave partials (lane-major: conflict-free)
    __shared__ float red[8][16][64];
    #pragma unroll
    for (int r = 0; r < 16; ++r) red[w][r][lane] = accA[r] + accB[r];
    __syncthreads();

    const int n = hn & 1, h = hn >> 1;
    float* outp = partA + ((size_t)(n * L_TOT + l0)) * MW + h * NF + c;
    #pragma unroll
    for (int j = 0; j < 2; ++j) {
        const int r = 2 * w + j;              // this wave finalizes C-regs 2w..2w+1
        float sv = 0.f;
        #pragma unroll
        for (int k = 0; k < 8; ++k) sv += red[k][r][lane];
        const int row = (r & 3) + 8 * (r >> 2) + 4 * hi;
        outp[(size_t)row * MW] = sv;
    }
}

// ---------------------------------------------------------------------------
// Kernel 4 (MFMA MLP): m=relu(relu(h@W1+b1)@W2+b2);
//   o = gamma*inorm(m+h)+beta; out[n,c,l]. Dual MFMA chains per layer.
// block = 512 (8 waves x 32-col groups), 32 rows/block, grid = 144
// ---------------------------------------------------------------------------
__global__ __launch_bounds__(512) void k_mlp(
    const float* __restrict__ partA,
    const __hip_bfloat16* __restrict__ W1t, const float* __restrict__ b1,
    const __hip_bfloat16* __restrict__ W2t, const float* __restrict__ b2,
    const float* __restrict__ gamma, const float* __restrict__ beta,
    float* __restrict__ out)
{
    const int blk = blockIdx.x;
    const int n  = blk / (L_TOT / RT);
    const int l0 = (blk % (L_TOT / RT)) * RT;
    const int tid = threadIdx.x;
    const int w = tid >> 6, lane = tid & 63;
    const int c = lane & 31, hi = lane >> 5;
    const int n0 = w * 32;

    __shared__ __align__(16) char smem[67584];
    float (*hsf)[MW] = reinterpret_cast<float (*)[MW]>(smem);
    __hip_bfloat16 (*hA)[264]  = reinterpret_cast<__hip_bfloat16 (*)[264]>(smem + 32768);
    __hip_bfloat16 (*msb)[264] = reinterpret_cast<__hip_bfloat16 (*)[264]>(smem + 49664);
    float (*ys)[MW] = reinterpret_cast<float (*)[MW]>(smem + 32768);
    float (*rs)[4]  = reinterpret_cast<float (*)[4]>(smem + 66560);
    float (*rs2)[4] = reinterpret_cast<float (*)[4]>(smem + 67072);

    for (int idx = tid; idx < RT * MW; idx += 512) {
        int r = idx >> 8, i = idx & 255;
        float v = partA[((size_t)n * L_TOT + l0 + r) * MW + i];
        hsf[r][i] = v;
        hA[r][i] = __float2bfloat16(v);
    }
    __syncthreads();

    // ---- layer 1 (dual chains) ----
    const float bb1 = b1[n0 + c];
    bf16x8 B1[16];
    #pragma unroll
    for (int k0 = 0; k0 < 16; ++k0)
        B1[k0] = *reinterpret_cast<const bf16x8*>(W1t + (size_t)(n0 + c) * MW + k0 * 16 + hi * 8);
    f32x16 a1 = {}, a1b = {};
    #pragma unroll
    for (int k0 = 0; k0 < 8; ++k0) {
        bf16x8 ae = *reinterpret_cast<const bf16x8*>(&hA[c][(2 * k0) * 16 + hi * 8]);
        bf16x8 ao = *reinterpret_cast<const bf16x8*>(&hA[c][(2 * k0 + 1) * 16 + hi * 8]);
        a1  = __builtin_amdgcn_mfma_f32_32x32x16_bf16(ae, B1[2 * k0],     a1,  0, 0, 0);
        a1b = __builtin_amdgcn_mfma_f32_32x32x16_bf16(ao, B1[2 * k0 + 1], a1b, 0, 0, 0);
    }
    #pragma unroll
    for (int r = 0; r < 16; ++r) {
        int row = (r & 3) + 8 * (r >> 2) + 4 * hi;
        msb[row][n0 + c] = __float2bfloat16(fmaxf(a1[r] + a1b[r] + bb1, 0.f));
    }
    __syncthreads();

    // ---- layer 2 + residual (dual chains) ----
    const float bb2 = b2[n0 + c];
    bf16x8 B2[16];
    #pragma unroll
    for (int k0 = 0; k0 < 16; ++k0)
        B2[k0] = *reinterpret_cast<const bf16x8*>(W2t + (size_t)(n0 + c) * MW + k0 * 16 + hi * 8);
    f32x16 a2 = {}, a2b = {};
    #pragma unroll
    for (int k0 = 0; k0 < 8; ++k0) {
        bf16x8 ae = *reinterpret_cast<const bf16x8*>(&msb[c][(2 * k0) * 16 + hi * 8]);
        bf16x8 ao = *reinterpret_cast<const bf16x8*>(&msb[c][(2 * k0 + 1) * 16 + hi * 8]);
        a2  = __builtin_amdgcn_mfma_f32_32x32x16_bf16(ae, B2[2 * k0],     a2,  0, 0, 0);
        a2b = __builtin_amdgcn_mfma_f32_32x32x16_bf16(ao, B2[2 * k0 + 1], a2b, 0, 0, 0);
    }
    float yv[16];
    #pragma unroll
    for (int r = 0; r < 16; ++r) {
        int row = (r & 3) + 8 * (r >> 2) + 4 * hi;
        yv[r] = fmaxf(a2[r] + a2b[r] + bb2, 0.f) + hsf[row][n0 + c];
    }
    __syncthreads();
    #pragma unroll
    for (int r = 0; r < 16; ++r) {
        int row = (r & 3) + 8 * (r >> 2) + 4 * hi;
        ys[row][n0 + c] = yv[r];
    }
    __syncthreads();

    // ---- instance norm over 256 channels per row + transposed store ----
    const int col = tid & 255;
    const int half = tid >> 8;
    const int wid = (tid >> 6) & 3;
    float vv[16];
    #pragma unroll
    for (int r = 0; r < 16; ++r) {
        float v = ys[half * 16 + r][col];
        vv[r] = v;
        float s = v, s2 = v * v;
        #pragma unroll
        for (int o = 32; o >= 1; o >>= 1) { s += __shfl_xor(s, o, 64); s2 += __shfl_xor(s2, o, 64); }
        if (lane == 0) { rs[half * 16 + r][wid] = s; rs2[half * 16 + r][wid] = s2; }
    }
    __syncthreads();
    const float g = gamma[col], be = beta[col];
    float ov[16];
    #pragma unroll
    for (int r = 0; r < 16; ++r) {
        int row = half * 16 + r;
        float s  = rs[row][0]  + rs[row][1]  + rs[row][2]  + rs[row][3];
        float s2 = rs2[row][0] + rs2[row][1] + rs2[row][2] + rs2[row][3];
        float mu  = s  * (1.f / MW);
        float var = s2 * (1.f / MW) - mu * mu;
        ov[r] = g * ((vv[r] - mu) * rsqrtf(var + EPSV)) + be;
    }
    float* ob = out + ((size_t)n * MW + col) * L_TOT + l0 + half * 16;
    #pragma unroll
    for (int q = 0; q < 4; ++q)
        reinterpret_cast<float4*>(ob)[q] =
            make_float4(ov[4 * q], ov[4 * q + 1], ov[4 * q + 2], ov[4 * q + 3]);
}

// ---------------------------------------------------------------------------
extern "C" void kernel_launch(void* const* d_in, const int* in_sizes, int n_in,
                              void* d_out, int out_size, void* d_ws, size_t ws_size,
                              hipStream_t stream) {
    const float* x  = (const float*)d_in[0];
    const float* Wq = (const float*)d_in[1];
    const float* bq = (const float*)d_in[2];
    const float* Wk = (const float*)d_in[3];
    const float* bk = (const float*)d_in[4];
    const float* Wv = (const float*)d_in[5];
    const float* bv = (const float*)d_in[6];
    const float* W1 = (const float*)d_in[7];
    const float* b1 = (const float*)d_in[8];
    const float* W2 = (const float*)d_in[9];
    const float* b2 = (const float*)d_in[10];
    const float* gm = (const float*)d_in[11];
    const float* bt = (const float*)d_in[12];
    float* out = (float*)d_out;

    const size_t QKVE = (size_t)16 * L_TOT * NF;   // 1,179,648 bf16 elems each
    const size_t XBE  = (size_t)NB * L_TOT * D_IN; // 294,912
    const size_t WQE  = (size_t)3 * NH * NF * D_IN;// 49,152
    const size_t WTE  = (size_t)MW * MW;           // 65,536 per matrix
    const size_t ZN = (size_t)CHS * 16 * L_TOT;

    __hip_bfloat16* Qb = (__hip_bfloat16*)d_ws;
    __hip_bfloat16* Kb = Qb + QKVE;
    __hip_bfloat16* Vt = Kb + QKVE;
    __hip_bfloat16* xb = Vt + QKVE;
    __hip_bfloat16* Wqkvt = xb + XBE;
    __hip_bfloat16* W1t = Wqkvt + WQE;
    __hip_bfloat16* W2t = W1t + WTE;
    float* zpart = (float*)(W2t + WTE);
    float* partA = zpart + ZN;

    k_prep<<<dim3(296), dim3(256), 0, stream>>>(
        x, Wq, Wk, Wv, W1, W2, xb, Wqkvt, W1t, W2t);
    k_proj<<<dim3(NSTRIP, NB, 2), dim3(256), 0, stream>>>(
        xb, Wqkvt, bq, bk, bv, Qb, Kb, Vt);
    k_stats<<<dim3(NSTRIP / 4, 16, CHS), dim3(256), 0, stream>>>(Qb, Kb, zpart);
    k_norm<<<dim3(NSTRIP, 16), dim3(256), 0, stream>>>(zpart, Vt);
    k_apply<<<dim3(NSTRIP, 16), dim3(512), 0, stream>>>(Qb, Kb, Vt, partA);
    k_mlp<<<dim3(NB * (L_TOT / RT)), dim3(512), 0, stream>>>(
        partA, W1t, b1, W2t, b2, gm, bt, out);
}